// Round 13
// baseline (593.094 us; speedup 1.0000x reference)
//
#include <hip/hip_runtime.h>
#include <math.h>

// eval-mode BatchNorm3d scale: np.float32(1/sqrt(1+1e-5))
#define BN_S 0.9999950000374997f

typedef _Float16 half8 __attribute__((ext_vector_type(8)));
typedef float f32x4 __attribute__((ext_vector_type(4)));

__device__ __forceinline__ float silu_f(float x) {
    return __fdividef(x, 1.0f + __expf(-x));
}

// global -> LDS async DMA, 16B per lane (lane-linear LDS destination)
__device__ __forceinline__ void gld16(const void* g, void* l) {
    __builtin_amdgcn_global_load_lds(
        (const __attribute__((address_space(1))) void*)g,
        (__attribute__((address_space(3))) void*)l, 16, 0, 0);
}

// ---------------------------------------------------------------------------
// Prep: W_mu = mw2 @ uw1, b_mu = mb2 @ uw1 + ub1, and W_em^T = (ew2 @ mw1[64:])^T
// split to fp16 hi/lo in the edge kernel's DMA/frag layout (XOR-swizzled).
// ---------------------------------------------------------------------------
__global__ __launch_bounds__(64) void prep_w_k(
    const float* __restrict__ ew2, const float* __restrict__ mw1,
    const float* __restrict__ mw2, const float* __restrict__ uw1,
    const float* __restrict__ mb2, const float* __restrict__ ub1,
    float* __restrict__ W_mu, float* __restrict__ b_mu,
    _Float16* __restrict__ wemt_h, _Float16* __restrict__ wemt_l)
{
    const int k = blockIdx.x, c = threadIdx.x;
    float s = 0.f;
    for (int m = 0; m < 64; m++) s = fmaf(ew2[k*64 + m], mw1[(64 + m)*64 + c], s);
    {
        const int q = k >> 5, kg = (k >> 3) & 3, jj = k & 7;
        const int sl = q*256 + c*4 + kg;
        const int p = sl ^ ((sl >> 3) & 7);
        const _Float16 h = (_Float16)s;
        const _Float16 l = (_Float16)(s - (float)h);
        wemt_h[p*8 + jj] = h;
        wemt_l[p*8 + jj] = l;
    }
    float s2 = 0.f;
    for (int m = 0; m < 64; m++) s2 = fmaf(mw2[k*64 + m], uw1[m*64 + c], s2);
    W_mu[k*64 + c] = s2;
    if (k == 0) {
        float s3 = ub1[c];
        for (int m = 0; m < 64; m++) s3 = fmaf(mb2[m], uw1[m*64 + c], s3);
        b_mu[c] = s3;
    }
}

// ---------------------------------------------------------------------------
__global__ __launch_bounds__(64) void prep_nodes_k(
    const float* __restrict__ node_embedding, const float* __restrict__ node_pos,
    const float* __restrict__ grid_pos, const float* __restrict__ ew1,
    const float* __restrict__ eb1, const float* __restrict__ mw1,
    const float* __restrict__ mb1, const float* __restrict__ eb2,
    float* __restrict__ a_node, float* __restrict__ g_vox, float* __restrict__ n_node)
{
    const int v = blockIdx.x, c = threadIdx.x;
    const float p0 = node_pos[v*3], p1 = node_pos[v*3 + 1], p2 = node_pos[v*3 + 2];
    a_node[v*64 + c] = fmaf(p0, ew1[c], fmaf(p1, ew1[64 + c], fmaf(p2, ew1[128 + c], eb1[c])));
    const float q0 = grid_pos[v*3], q1 = grid_pos[v*3 + 1], q2 = grid_pos[v*3 + 2];
    g_vox[v*64 + c] = fmaf(q0, ew1[192 + c], fmaf(q1, ew1[256 + c], q2 * ew1[320 + c]));
    float s = mb1[c];
    for (int k = 0; k < 64; k++) s = fmaf(node_embedding[v*64 + k], mw1[k*64 + c], s);
    for (int k = 0; k < 64; k++) s = fmaf(eb2[k], mw1[(64 + k)*64 + c], s);
    n_node[v*64 + c] = s;
}

// ---------------------------------------------------------------------------
// Weight transpose + fp16 hi/lo split into conv layout (unchanged):
// per (tap, coG64, ch): 2048 f16 = [co64][ci32] with 16B-slot XOR swizzle.
// ---------------------------------------------------------------------------
template<int K3, int NCOG, int NCH>
__global__ __launch_bounds__(256) void wsplit_k(
    const float* __restrict__ w, _Float16* __restrict__ dh, _Float16* __restrict__ dl,
    int CI)
{
    __shared__ float s[32*K3];
    const int co = blockIdx.x, cig = blockIdx.y, t = threadIdx.x;
    const float* src = w + ((size_t)co*CI + cig*32)*K3;
    for (int m = t; m < 32*K3; m += 256) s[m] = src[m];
    __syncthreads();
    const int coG = co >> 6, col = co & 63;
    for (int m = t; m < 32*K3; m += 256) {
        const int tap = m >> 5, cil = m & 31;
        const float x = s[cil*K3 + tap];
        const _Float16 h = (_Float16)x;
        const _Float16 l = (_Float16)(x - (float)h);
        const int b = cil >> 3, jj = cil & 7;
        const int sl = col*4 + b;
        const int p = sl ^ ((sl >> 3) & 7);
        const size_t base = ((size_t)(tap*NCOG + coG)*NCH + cig) * 2048;
        dh[base + p*8 + jj] = h;
        dl[base + p*8 + jj] = l;
    }
}

// ---------------------------------------------------------------------------
// Edge kernel v3 (unchanged from R12 — conflicts now 0, absmax 0.0).
// ---------------------------------------------------------------------------
__global__ __launch_bounds__(256, 3) void edge_kernel(
    const int* __restrict__ edge_i,
    const float* __restrict__ a_node, const float* __restrict__ g_vox,
    const float* __restrict__ n_node,
    const _Float16* __restrict__ wemt_h, const _Float16* __restrict__ wemt_l,
    const float* __restrict__ W_mu, const float* __restrict__ b_mu,
    const float* __restrict__ uw2, const float* __restrict__ ub2,
    _Float16* __restrict__ x0h, _Float16* __restrict__ x0l)
{
    __shared__ __align__(16) _Float16 sAh[4096], sAl[4096];
    __shared__ __align__(16) _Float16 sBh[2][4096], sBl[2][4096];
    __shared__ float sV1[64], sV2[64], sRed[4*64];

    const int j = blockIdx.x, t = threadIdx.x;
    const int lane = t & 63, wv = t >> 6, ln15 = lane & 15, kg = lane >> 4;
    const int ebase = j << 8;

    gld16(wemt_h + t*8, &sAh[t*8]);
    gld16(wemt_h + 2048 + t*8, &sAh[2048 + t*8]);
    gld16(wemt_l + t*8, &sAl[t*8]);
    gld16(wemt_l + 2048 + t*8, &sAl[2048 + t*8]);

    const int r = t >> 2, sub = t & 3;
    float4 gv4[4];
    #pragma unroll
    for (int m4 = 0; m4 < 4; m4++)
        gv4[m4] = *(const float4*)&g_vox[j*64 + sub*16 + m4*4];

    // tile-0 prefetch (A rows + N cols)
    float4 A[2][4], N[2][4];
    {
        const int iA = edge_i[ebase + r];
        #pragma unroll
        for (int m4 = 0; m4 < 4; m4++)
            A[0][m4] = *(const float4*)&a_node[(size_t)iA*64 + sub*16 + m4*4];
        #pragma unroll
        for (int eF = 0; eF < 4; eF++) {
            const int ieX = edge_i[ebase + eF*16 + ln15];
            N[0][eF] = *(const float4*)&n_node[(size_t)ieX*64 + wv*16 + kg*4];
        }
    }

    asm volatile("s_waitcnt vmcnt(0)" ::: "memory");
    __syncthreads();

    float psum[4] = {0.f, 0.f, 0.f, 0.f};

    #pragma unroll
    for (int T = 0; T < 4; T++) {
        const int par = T & 1;
        // ---- Phase A: silu + packed fp16 hi/lo split -> sB[par] (swizzled) ----
        {
            float s1v[16];
            #pragma unroll
            for (int m4 = 0; m4 < 4; m4++) {
                const float4 a = A[par][m4], g = gv4[m4];
                s1v[m4*4 + 0] = silu_f(a.x + g.x);
                s1v[m4*4 + 1] = silu_f(a.y + g.y);
                s1v[m4*4 + 2] = silu_f(a.z + g.z);
                s1v[m4*4 + 3] = silu_f(a.w + g.w);
            }
            uint32_t hw[8], lw[8];
            #pragma unroll
            for (int m = 0; m < 8; m++) {
                const auto hp = __builtin_amdgcn_cvt_pkrtz(s1v[2*m], s1v[2*m + 1]);
                const float h0f = (float)hp[0], h1f = (float)hp[1];
                const auto lp = __builtin_amdgcn_cvt_pkrtz(s1v[2*m] - h0f, s1v[2*m + 1] - h1f);
                hw[m] = __builtin_bit_cast(uint32_t, hp);
                lw[m] = __builtin_bit_cast(uint32_t, lp);
            }
            const int q = sub >> 1, kg0 = (sub & 1) * 2;
            const int sl0 = (q*4 + kg0)*64 + r;
            const int sl1 = sl0 + 64;
            const int p0 = sl0 ^ ((sl0 >> 6) & 7);
            const int p1 = sl1 ^ ((sl1 >> 6) & 7);
            uint4 u;
            u.x = hw[0]; u.y = hw[1]; u.z = hw[2]; u.w = hw[3];
            *(uint4*)&sBh[par][p0*8] = u;
            u.x = hw[4]; u.y = hw[5]; u.z = hw[6]; u.w = hw[7];
            *(uint4*)&sBh[par][p1*8] = u;
            u.x = lw[0]; u.y = lw[1]; u.z = lw[2]; u.w = lw[3];
            *(uint4*)&sBl[par][p0*8] = u;
            u.x = lw[4]; u.y = lw[5]; u.z = lw[6]; u.w = lw[7];
            *(uint4*)&sBl[par][p1*8] = u;
        }
        // ---- prefetch tile T+1 (flies under barrier + Phase B) ----
        if (T < 3) {
            const int b1 = ebase + (T + 1)*64;
            const int iA = edge_i[b1 + r];
            #pragma unroll
            for (int m4 = 0; m4 < 4; m4++)
                A[par ^ 1][m4] = *(const float4*)&a_node[(size_t)iA*64 + sub*16 + m4*4];
            #pragma unroll
            for (int eF = 0; eF < 4; eF++) {
                const int ieX = edge_i[b1 + eF*16 + ln15];
                N[par ^ 1][eF] = *(const float4*)&n_node[(size_t)ieX*64 + wv*16 + kg*4];
            }
        }
        __syncthreads();   // sB[par] visible; overwrite of par safe (rendezvous)
        // ---- Phase B ----
        #pragma unroll
        for (int eF = 0; eF < 4; eF++) {
            const int e = eF*16 + ln15;
            f32x4 acc;
            {
                const float4 nv = N[par][eF];
                acc[0] = nv.x; acc[1] = nv.y; acc[2] = nv.z; acc[3] = nv.w;
            }
            #pragma unroll
            for (int q2 = 0; q2 < 2; q2++) {
                const int sa = q2*256 + (wv*16 + ln15)*4 + kg;
                const int pa = sa ^ ((sa >> 3) & 7);
                const half8 Ah = *(const half8*)&sAh[pa*8];
                const half8 Al = *(const half8*)&sAl[pa*8];
                const int sbs = (q2*4 + kg)*64 + e;
                const int pb = sbs ^ ((sbs >> 6) & 7);
                const half8 Bh = *(const half8*)&sBh[par][pb*8];
                const half8 Bl = *(const half8*)&sBl[par][pb*8];
                acc = __builtin_amdgcn_mfma_f32_16x16x32_f16(Ah, Bh, acc, 0, 0, 0);
                acc = __builtin_amdgcn_mfma_f32_16x16x32_f16(Ah, Bl, acc, 0, 0, 0);
                acc = __builtin_amdgcn_mfma_f32_16x16x32_f16(Al, Bh, acc, 0, 0, 0);
            }
            #pragma unroll
            for (int rg = 0; rg < 4; rg++) psum[rg] += silu_f(acc[rg]);
        }
    }

    // mean across the 16 e-columns held by ln15 lanes
    #pragma unroll
    for (int rg = 0; rg < 4; rg++) {
        float v = psum[rg];
        v += __shfl_xor(v, 1, 64); v += __shfl_xor(v, 2, 64);
        v += __shfl_xor(v, 4, 64); v += __shfl_xor(v, 8, 64);
        psum[rg] = v;
    }
    __syncthreads();   // all Phase-B LDS reads done before tail reuse
    if (ln15 == 0) {
        #pragma unroll
        for (int rg = 0; rg < 4; rg++)
            sV1[wv*16 + kg*4 + rg] = psum[rg] * (1.0f / 256.0f);
    }
    __syncthreads();
    // ---- tail matvec 1 (all 256 threads: c = t&63, k-quarter = t>>6) ----
    {
        const int c = t & 63, part = t >> 6;
        float h = (part == 0) ? b_mu[c] : 0.f;
        #pragma unroll
        for (int k2 = 0; k2 < 16; k2++) {
            const int k = part*16 + k2;
            h = fmaf(sV1[k], W_mu[k*64 + c], h);
        }
        sRed[part*64 + c] = h;
    }
    __syncthreads();
    if (t < 64)
        sV2[t] = silu_f(sRed[t] + sRed[64 + t] + sRed[128 + t] + sRed[192 + t]);
    __syncthreads();
    // ---- tail matvec 2 ----
    {
        const int c = t & 63, part = t >> 6;
        float g = (part == 0) ? ub2[c] : 0.f;
        #pragma unroll
        for (int k2 = 0; k2 < 16; k2++) {
            const int k = part*16 + k2;
            g = fmaf(sV2[k], uw2[k*64 + c], g);
        }
        sRed[part*64 + c] = g;
    }
    __syncthreads();
    if (t < 64) {
        const float val = (sRed[t] + sRed[64 + t] + sRed[128 + t] + sRed[192 + t]) * BN_S;
        const _Float16 hh = (_Float16)val;
        const _Float16 ll = (_Float16)(val - (float)hh);
        const int c = t, zz = j >> 8, v = j & 255;
        const int oct = (c >> 3) & 3;
        const int vsw = v ^ (oct << 1);   // kg bank-alias swizzle
        const size_t a16 = ((size_t)((c >> 5)*16 + zz)*1024 + oct*256 + vsw)*8 + (c & 7);
        x0h[a16] = hh; x0l[a16] = ll;
    }
}

// ---------------------------------------------------------------------------
// Conv3D via MFMA shift-GEMM v9: single-buffer X (33KB LDS), A AND B register
// double-buffers — tap t's 24-MFMA burst covers tap t+1's ds_read + global
// load latency. 3 blocks/CU (VGPR ~155). Manual 2x tap unroll, named reg
// sets (all indices compile-time). kg-XOR B slots (conflict-free).
// ---------------------------------------------------------------------------
template<int KK, int CI, int NCO32, int CIS>
__global__ __launch_bounds__(256, 3) void conv_mfma_k(
    const _Float16* __restrict__ xh, const _Float16* __restrict__ xl,
    const _Float16* __restrict__ wh, const _Float16* __restrict__ wl,
    float* __restrict__ slab)
{
    constexpr int P = KK/2, K2 = KK*KK, NCH = CI/32, NCHS = NCH/CIS;
    constexpr int CO = NCO32*32, NCOG64 = NCO32/2;
    const int d0 = blockIdx.x, coG32 = blockIdx.y;
    const int co64G = coG32 >> 1, coHalf = coG32 & 1;
    const int cis = blockIdx.z / KK, kd = blockIdx.z % KK;
    const int t = threadIdx.x;
    const int lane = t & 63, wv = t >> 6;
    const int ln15 = lane & 15, kg = lane >> 4;

    float* sout = slab + ((size_t)blockIdx.z*CO + coG32*32)*4096 + d0*256;
    const int z = d0 + kd - P;
    if ((unsigned)z >= 16u) {   // OOB depth plane -> zero partial
        for (int m = t; m < 32*256; m += 256)
            sout[(size_t)(m >> 8)*4096 + (m & 255)] = 0.f;
        return;
    }

    __shared__ __align__(16) _Float16 sXh[8192];   // 16 KB
    __shared__ __align__(16) _Float16 sXl[8192];   // 16 KB
    __shared__ __align__(16) _Float16 zb[8];
    if (t < 8) zb[t] = (_Float16)0.f;

    int aoff[2];
    #pragma unroll
    for (int cf = 0; cf < 2; cf++) {
        const int s = (coHalf*32 + cf*16 + ln15)*4 + kg;
        aoff[cf] = (s ^ ((s >> 3) & 7)) * 8;
    }

    auto stage_X = [&](int ch) {
        const size_t b16 = ((size_t)ch*16 + z) * 8192;
        #pragma unroll
        for (int q = 0; q < 4; q++) {
            gld16(xh + b16 + (q*256 + t)*8, &sXh[(q*256 + t)*8]);
            gld16(xl + b16 + (q*256 + t)*8, &sXl[(q*256 + t)*8]);
        }
    };
    auto loadA = [&](int ch, int t2, half8* Ah, half8* Al) {
        const size_t b = ((size_t)((kd*K2 + t2)*NCOG64 + co64G)*NCH + ch) * 2048;
        #pragma unroll
        for (int cf = 0; cf < 2; cf++) {
            Ah[cf] = *(const half8*)&wh[b + aoff[cf]];
            Al[cf] = *(const half8*)&wl[b + aoff[cf]];
        }
    };
    auto loadB = [&](int t2, half8* Bh, half8* Bl) {
        const int kh = t2 / KK, kw = t2 - kh*KK;
        const int w_in = ln15 + kw - P;
        const bool okw = (unsigned)w_in < 16u;
        #pragma unroll
        for (int f = 0; f < 4; f++) {
            const int h_in = wv*4 + f + kh - P;   // wave-uniform
            if ((unsigned)h_in < 16u) {
                const int slot = okw ? (kg*256 + h_in*16 + (w_in ^ (kg << 1))) : 0;
                const _Float16* ph = okw ? &sXh[slot*8] : zb;
                const _Float16* pl = okw ? &sXl[slot*8] : zb;
                Bh[f] = *(const half8*)ph;
                Bl[f] = *(const half8*)pl;
            }
        }
    };

    f32x4 acc[2][4];
    #pragma unroll
    for (int a = 0; a < 2; a++)
        #pragma unroll
        for (int b = 0; b < 4; b++)
            #pragma unroll
            for (int r2 = 0; r2 < 4; r2++) acc[a][b][r2] = 0.f;

    auto burst = [&](int t2, const half8* Ah, const half8* Al,
                     const half8* Bh, const half8* Bl) {
        const int kh = t2 / KK;
        __builtin_amdgcn_s_setprio(1);
        #pragma unroll
        for (int f = 0; f < 4; f++) {
            const int h_in = wv*4 + f + kh - P;
            if ((unsigned)h_in < 16u) {
                #pragma unroll
                for (int cf = 0; cf < 2; cf++) {
                    acc[cf][f] = __builtin_amdgcn_mfma_f32_16x16x32_f16(Ah[cf], Bh[f], acc[cf][f], 0, 0, 0);
                    acc[cf][f] = __builtin_amdgcn_mfma_f32_16x16x32_f16(Ah[cf], Bl[f], acc[cf][f], 0, 0, 0);
                    acc[cf][f] = __builtin_amdgcn_mfma_f32_16x16x32_f16(Al[cf], Bh[f], acc[cf][f], 0, 0, 0);
                }
            }
        }
        __builtin_amdgcn_s_setprio(0);
    };

    const int ch0 = cis * NCHS;
    half8 A0h[2], A0l[2], A1h[2], A1l[2];
    half8 B0h[4], B0l[4], B1h[4], B1l[4];
    stage_X(ch0);
    loadA(ch0, 0, A0h, A0l);
    asm volatile("s_waitcnt vmcnt(0)" ::: "memory");
    __syncthreads();

    for (int cc = 0; cc < NCHS; cc++) {
        const int ch = ch0 + cc;
        loadB(0, B0h, B0l);
        int t2 = 0;
        for (; t2 + 2 < K2; t2 += 2) {
            // tap t2 (set0); prefetch t2+1 into set1 BEFORE the burst
            loadA(ch, t2 + 1, A1h, A1l);
            loadB(t2 + 1, B1h, B1l);
            burst(t2, A0h, A0l, B0h, B0l);
            // tap t2+1 (set1); prefetch t2+2 into set0
            loadA(ch, t2 + 2, A0h, A0l);
            loadB(t2 + 2, B0h, B0l);
            burst(t2 + 1, A1h, A1l, B1h, B1l);
        }
        // tail tap K2-1 held in set0 (K2 odd)
        if (cc + 1 < NCHS) loadA(ch + 1, 0, A1h, A1l);
        burst(K2 - 1, A0h, A0l, B0h, B0l);
        if (cc + 1 < NCHS) {
            #pragma unroll
            for (int cf = 0; cf < 2; cf++) { A0h[cf] = A1h[cf]; A0l[cf] = A1l[cf]; }
            __syncthreads();                               // all reads of sX done
            stage_X(ch + 1);
            asm volatile("s_waitcnt vmcnt(0)" ::: "memory");
            __syncthreads();                               // new chunk landed
        }
    }

    #pragma unroll
    for (int cf = 0; cf < 2; cf++)
        #pragma unroll
        for (int f = 0; f < 4; f++)
            #pragma unroll
            for (int r2 = 0; r2 < 4; r2++)
                sout[(size_t)(cf*16 + kg*4 + r2)*4096 + wv*64 + f*16 + ln15] = acc[cf][f][r2];
}

// ---------------------------------------------------------------------------
// Reduce S kd/cis-slabs + BN (+residual) (+relu); emit fp32 / fp16-split /
// poolmax partials. grid(16 z, CO/8). OUT=1 applies the kg-XOR vox swizzle.
// ---------------------------------------------------------------------------
template<int S, int RMODE, int OUT>
__global__ __launch_bounds__(256) void reduce_k(
    const float* __restrict__ pbuf, const float* __restrict__ addsrc,
    float* __restrict__ outf, _Float16* __restrict__ oh, _Float16* __restrict__ ol,
    int CO)
{
    const int z = blockIdx.x, c8 = blockIdx.y, v = threadIdx.x;
    float val[8];
    #pragma unroll
    for (int jj = 0; jj < 8; jj++) {
        const int c = c8*8 + jj;
        float a = 0.f;
        #pragma unroll
        for (int s = 0; s < S; s++)
            a += pbuf[((size_t)s*CO + c)*4096 + z*256 + v];
        a *= BN_S;
        if (RMODE == 3) a += addsrc[(size_t)c*4096 + z*256 + v];
        if (RMODE != 2) a = fmaxf(a, 0.f);
        val[jj] = a;
    }
    if (OUT == 0) {
        #pragma unroll
        for (int jj = 0; jj < 8; jj++)
            outf[(size_t)(c8*8 + jj)*4096 + z*256 + v] = val[jj];
    } else if (OUT == 1) {
        half8 hv, lv;
        #pragma unroll
        for (int jj = 0; jj < 8; jj++) {
            hv[jj] = (_Float16)val[jj];
            lv[jj] = (_Float16)(val[jj] - (float)hv[jj]);
        }
        const int oct = c8 & 3;
        const int vsw = v ^ (oct << 1);   // kg bank-alias swizzle
        const size_t a16 = ((size_t)((c8 >> 2)*16 + z)*1024 + oct*256 + vsw)*8;
        *(half8*)&oh[a16] = hv;
        *(half8*)&ol[a16] = lv;
    } else {
        __shared__ float sm[4][8];
        #pragma unroll
        for (int jj = 0; jj < 8; jj++) {
            float m = val[jj];
            m = fmaxf(m, __shfl_xor(m, 1, 64));  m = fmaxf(m, __shfl_xor(m, 2, 64));
            m = fmaxf(m, __shfl_xor(m, 4, 64));  m = fmaxf(m, __shfl_xor(m, 8, 64));
            m = fmaxf(m, __shfl_xor(m, 16, 64)); m = fmaxf(m, __shfl_xor(m, 32, 64));
            if ((v & 63) == 0) sm[v >> 6][jj] = m;
        }
        __syncthreads();
        if (v < 8) {
            const float m = fmaxf(fmaxf(sm[0][v], sm[1][v]), fmaxf(sm[2][v], sm[3][v]));
            outf[z*CO + c8*8 + v] = m;
        }
    }
}

// ---------------------------------------------------------------------------
__global__ __launch_bounds__(256) void fc_k(
    const float* __restrict__ pp, const float* __restrict__ fcw,
    const float* __restrict__ fcb, float* __restrict__ out)
{
    __shared__ float sp[256];
    const int t = threadIdx.x;
    float m = pp[t];
    for (int zz = 1; zz < 16; zz++) m = fmaxf(m, pp[zz*256 + t]);
    sp[t] = m;
    __syncthreads();
    if (t < 20) {
        float s = fcb[t];
        for (int c = 0; c < 256; c++) s = fmaf(sp[c], fcw[c*20 + t], s);
        out[t] = s;
    }
}

// ---------------------------------------------------------------------------
extern "C" void kernel_launch(void* const* d_in, const int* in_sizes, int n_in,
                              void* d_out, int out_size, void* d_ws, size_t ws_size,
                              hipStream_t stream)
{
    const float* node_embedding = (const float*)d_in[0];
    const float* node_pos       = (const float*)d_in[1];
    const float* grid_pos       = (const float*)d_in[2];
    const int*   edge_index     = (const int*)d_in[3];
    const float* ew1 = (const float*)d_in[4];
    const float* eb1 = (const float*)d_in[5];
    const float* ew2 = (const float*)d_in[6];
    const float* eb2 = (const float*)d_in[7];
    const float* mw1 = (const float*)d_in[8];
    const float* mb1 = (const float*)d_in[9];
    const float* mw2 = (const float*)d_in[10];
    const float* mb2 = (const float*)d_in[11];
    const float* uw1 = (const float*)d_in[12];
    const float* ub1 = (const float*)d_in[13];
    const float* uw2 = (const float*)d_in[14];
    const float* ub2 = (const float*)d_in[15];
    const float* c1a = (const float*)d_in[16];
    const float* c1b = (const float*)d_in[17];
    const float* c1s = (const float*)d_in[18];
    const float* c2a = (const float*)d_in[19];
    const float* c2b = (const float*)d_in[20];
    const float* c2s = (const float*)d_in[21];
    const float* c3a = (const float*)d_in[22];
    const float* c3b = (const float*)d_in[23];
    const float* c3s = (const float*)d_in[24];
    const float* fcw = (const float*)d_in[25];
    const float* fcb = (const float*)d_in[26];
    float* out = (float*)d_out;
    const int* edge_i = edge_index;   // row 0

    float* ws = (float*)d_ws;
    float* a_node = ws;                ws += 262144;
    float* g_vox  = ws;                ws += 262144;
    float* n_node = ws;                ws += 262144;
    float* W_mu   = ws;                ws += 4096;
    float* b_mu   = ws;                ws += 64;
    _Float16* wemt_h = (_Float16*)ws;  ws += 2048;
    _Float16* wemt_l = (_Float16*)ws;  ws += 2048;
    _Float16* x0h = (_Float16*)ws;     ws += 131072;
    _Float16* x0l = (_Float16*)ws;     ws += 131072;
    _Float16* t2h = (_Float16*)ws;     ws += 262144;
    _Float16* t2l = (_Float16*)ws;     ws += 262144;
    _Float16* x2h = (_Float16*)ws;     ws += 262144;
    _Float16* x2l = (_Float16*)ws;     ws += 262144;
    _Float16* t3h = (_Float16*)ws;     ws += 524288;
    _Float16* t3l = (_Float16*)ws;     ws += 524288;
    float* u2 = ws;                    ws += 524288;
    float* u3 = ws;                    ws += 1048576;
    float* slab = ws;                  ws += 5242880;
    float* poolPart = ws;              ws += 4096;
    _Float16* wh = (_Float16*)ws;      ws += 4585472;   // 9170944 f16
    _Float16* wl = (_Float16*)ws;      ws += 4585472;
    // aliases valid after edge_kernel (node tables dead):
    _Float16* t1h = (_Float16*)a_node;
    _Float16* t1l = (_Float16*)(a_node + 131072);
    float* u1 = g_vox;
    _Float16* x1h = (_Float16*)n_node;
    _Float16* x1l = (_Float16*)(n_node + 131072);

    _Float16* w1a_h = wh + 0;       _Float16* w1a_l = wl + 0;
    _Float16* w1b_h = wh + 110592;  _Float16* w1b_l = wl + 110592;
    _Float16* w1s_h = wh + 221184;  _Float16* w1s_l = wl + 221184;
    _Float16* w2a_h = wh + 733184;  _Float16* w2a_l = wl + 733184;
    _Float16* w2b_h = wh + 954368;  _Float16* w2b_l = wl + 954368;
    _Float16* w2s_h = wh + 1396736; _Float16* w2s_l = wl + 1396736;
    _Float16* w3a_h = wh + 2420736; _Float16* w3a_l = wl + 2420736;
    _Float16* w3b_h = wh + 3305472; _Float16* w3b_l = wl + 3305472;
    _Float16* w3s_h = wh + 5074944; _Float16* w3s_l = wl + 5074944;

    // ---- weight transpose + split ----
    hipLaunchKernelGGL((wsplit_k<27,1,2>),  dim3(64,2),  dim3(256), 0, stream, c1a, w1a_h, w1a_l, 64);
    hipLaunchKernelGGL((wsplit_k<27,1,2>),  dim3(64,2),  dim3(256), 0, stream, c1b, w1b_h, w1b_l, 64);
    hipLaunchKernelGGL((wsplit_k<125,1,2>), dim3(64,2),  dim3(256), 0, stream, c1s, w1s_h, w1s_l, 64);
    hipLaunchKernelGGL((wsplit_k<27,2,2>),  dim3(128,2), dim3(256), 0, stream, c2a, w2a_h, w2a_l, 64);
    hipLaunchKernelGGL((wsplit_k<27,2,4>),  dim3(128,4), dim3(256), 0, stream, c2b, w2b_h, w2b_l, 128);
    hipLaunchKernelGGL((wsplit_k<125,2,2>), dim3(128,2), dim3(256), 0, stream, c2s, w2s_h, w2s_l, 64);
    hipLaunchKernelGGL((wsplit_k<27,4,4>),  dim3(256,4), dim3(256), 0, stream, c3a, w3a_h, w3a_l, 128);
    hipLaunchKernelGGL((wsplit_k<27,4,8>),  dim3(256,8), dim3(256), 0, stream, c3b, w3b_h, w3b_l, 256);
    hipLaunchKernelGGL((wsplit_k<125,4,4>), dim3(256,4), dim3(256), 0, stream, c3s, w3s_h, w3s_l, 128);

    // ---- MPNN ----
    hipLaunchKernelGGL(prep_w_k, dim3(64), dim3(64), 0, stream,
                       ew2, mw1, mw2, uw1, mb2, ub1, W_mu, b_mu, wemt_h, wemt_l);
    hipLaunchKernelGGL(prep_nodes_k, dim3(4096), dim3(64), 0, stream,
                       node_embedding, node_pos, grid_pos, ew1, eb1, mw1, mb1, eb2,
                       a_node, g_vox, n_node);
    hipLaunchKernelGGL(edge_kernel, dim3(4096), dim3(256), 0, stream,
                       edge_i, a_node, g_vox, n_node, wemt_h, wemt_l,
                       W_mu, b_mu, uw2, ub2, x0h, x0l);

    // ---- ResNet3D ----
    // Block 1: 64 -> 64  (ci-split 2: S = 2*KK slabs)
    hipLaunchKernelGGL((conv_mfma_k<3,64,2,2>), dim3(16,2,6), dim3(256), 0, stream, x0h, x0l, w1a_h, w1a_l, slab);
    hipLaunchKernelGGL((reduce_k<6,1,1>), dim3(16,8), dim3(256), 0, stream, slab, (const float*)nullptr, (float*)nullptr, t1h, t1l, 64);
    hipLaunchKernelGGL((conv_mfma_k<3,64,2,2>), dim3(16,2,6), dim3(256), 0, stream, t1h, t1l, w1b_h, w1b_l, slab);
    hipLaunchKernelGGL((reduce_k<6,2,0>), dim3(16,8), dim3(256), 0, stream, slab, (const float*)nullptr, u1, (_Float16*)nullptr, (_Float16*)nullptr, 64);
    hipLaunchKernelGGL((conv_mfma_k<5,64,2,2>), dim3(16,2,10), dim3(256), 0, stream, x0h, x0l, w1s_h, w1s_l, slab);
    hipLaunchKernelGGL((reduce_k<10,3,1>), dim3(16,8), dim3(256), 0, stream, slab, u1, (float*)nullptr, x1h, x1l, 64);
    // Block 2: 64 -> 128
    hipLaunchKernelGGL((conv_mfma_k<3,64,4,2>), dim3(16,4,6), dim3(256), 0, stream, x1h, x1l, w2a_h, w2a_l, slab);
    hipLaunchKernelGGL((reduce_k<6,1,1>), dim3(16,16), dim3(256), 0, stream, slab, (const float*)nullptr, (float*)nullptr, t2h, t2l, 128);
    hipLaunchKernelGGL((conv_mfma_k<3,128,4,2>), dim3(16,4,6), dim3(256), 0, stream, t2h, t2l, w2b_h, w2b_l, slab);
    hipLaunchKernelGGL((reduce_k<6,2,0>), dim3(16,16), dim3(256), 0, stream, slab, (const float*)nullptr, u2, (_Float16*)nullptr, (_Float16*)nullptr, 128);
    hipLaunchKernelGGL((conv_mfma_k<5,64,4,2>), dim3(16,4,10), dim3(256), 0, stream, x1h, x1l, w2s_h, w2s_l, slab);
    hipLaunchKernelGGL((reduce_k<10,3,1>), dim3(16,16), dim3(256), 0, stream, slab, u2, (float*)nullptr, x2h, x2l, 128);
    // Block 3: 128 -> 256  (no ci-split: slab budget)
    hipLaunchKernelGGL((conv_mfma_k<3,128,8,1>), dim3(16,8,3), dim3(256), 0, stream, x2h, x2l, w3a_h, w3a_l, slab);
    hipLaunchKernelGGL((reduce_k<3,1,1>), dim3(16,32), dim3(256), 0, stream, slab, (const float*)nullptr, (float*)nullptr, t3h, t3l, 256);
    hipLaunchKernelGGL((conv_mfma_k<3,256,8,1>), dim3(16,8,3), dim3(256), 0, stream, t3h, t3l, w3b_h, w3b_l, slab);
    hipLaunchKernelGGL((reduce_k<3,2,0>), dim3(16,32), dim3(256), 0, stream, slab, (const float*)nullptr, u3, (_Float16*)nullptr, (_Float16*)nullptr, 256);
    hipLaunchKernelGGL((conv_mfma_k<5,128,8,1>), dim3(16,8,5), dim3(256), 0, stream, x2h, x2l, w3s_h, w3s_l, slab);
    hipLaunchKernelGGL((reduce_k<5,3,2>), dim3(16,32), dim3(256), 0, stream, slab, u3, poolPart, (_Float16*)nullptr, (_Float16*)nullptr, 256);

    hipLaunchKernelGGL(fc_k, dim3(1), dim3(256), 0, stream, poolPart, fcw, fcb, out);

    (void)in_sizes; (void)n_in; (void)out_size; (void)ws_size;
}

// Round 14
// 538.158 us; speedup vs baseline: 1.1021x; 1.1021x over previous
//
#include <hip/hip_runtime.h>
#include <math.h>

// eval-mode BatchNorm3d scale: np.float32(1/sqrt(1+1e-5))
#define BN_S 0.9999950000374997f

typedef _Float16 half8 __attribute__((ext_vector_type(8)));
typedef float f32x4 __attribute__((ext_vector_type(4)));

__device__ __forceinline__ float silu_f(float x) {
    return __fdividef(x, 1.0f + __expf(-x));
}

// global -> LDS async DMA, 16B per lane (lane-linear LDS destination)
__device__ __forceinline__ void gld16(const void* g, void* l) {
    __builtin_amdgcn_global_load_lds(
        (const __attribute__((address_space(1))) void*)g,
        (__attribute__((address_space(3))) void*)l, 16, 0, 0);
}

// ---------------------------------------------------------------------------
// Prep: W_mu = mw2 @ uw1, b_mu = mb2 @ uw1 + ub1, and W_em^T = (ew2 @ mw1[64:])^T
// split to fp16 hi/lo in the edge kernel's DMA/frag layout (XOR-swizzled).
// ---------------------------------------------------------------------------
__global__ __launch_bounds__(64) void prep_w_k(
    const float* __restrict__ ew2, const float* __restrict__ mw1,
    const float* __restrict__ mw2, const float* __restrict__ uw1,
    const float* __restrict__ mb2, const float* __restrict__ ub1,
    float* __restrict__ W_mu, float* __restrict__ b_mu,
    _Float16* __restrict__ wemt_h, _Float16* __restrict__ wemt_l)
{
    const int k = blockIdx.x, c = threadIdx.x;
    float s = 0.f;
    for (int m = 0; m < 64; m++) s = fmaf(ew2[k*64 + m], mw1[(64 + m)*64 + c], s);
    {
        const int q = k >> 5, kg = (k >> 3) & 3, jj = k & 7;
        const int sl = q*256 + c*4 + kg;
        const int p = sl ^ ((sl >> 3) & 7);
        const _Float16 h = (_Float16)s;
        const _Float16 l = (_Float16)(s - (float)h);
        wemt_h[p*8 + jj] = h;
        wemt_l[p*8 + jj] = l;
    }
    float s2 = 0.f;
    for (int m = 0; m < 64; m++) s2 = fmaf(mw2[k*64 + m], uw1[m*64 + c], s2);
    W_mu[k*64 + c] = s2;
    if (k == 0) {
        float s3 = ub1[c];
        for (int m = 0; m < 64; m++) s3 = fmaf(mb2[m], uw1[m*64 + c], s3);
        b_mu[c] = s3;
    }
}

// ---------------------------------------------------------------------------
__global__ __launch_bounds__(64) void prep_nodes_k(
    const float* __restrict__ node_embedding, const float* __restrict__ node_pos,
    const float* __restrict__ grid_pos, const float* __restrict__ ew1,
    const float* __restrict__ eb1, const float* __restrict__ mw1,
    const float* __restrict__ mb1, const float* __restrict__ eb2,
    float* __restrict__ a_node, float* __restrict__ g_vox, float* __restrict__ n_node)
{
    const int v = blockIdx.x, c = threadIdx.x;
    const float p0 = node_pos[v*3], p1 = node_pos[v*3 + 1], p2 = node_pos[v*3 + 2];
    a_node[v*64 + c] = fmaf(p0, ew1[c], fmaf(p1, ew1[64 + c], fmaf(p2, ew1[128 + c], eb1[c])));
    const float q0 = grid_pos[v*3], q1 = grid_pos[v*3 + 1], q2 = grid_pos[v*3 + 2];
    g_vox[v*64 + c] = fmaf(q0, ew1[192 + c], fmaf(q1, ew1[256 + c], q2 * ew1[320 + c]));
    float s = mb1[c];
    for (int k = 0; k < 64; k++) s = fmaf(node_embedding[v*64 + k], mw1[k*64 + c], s);
    for (int k = 0; k < 64; k++) s = fmaf(eb2[k], mw1[(64 + k)*64 + c], s);
    n_node[v*64 + c] = s;
}

// ---------------------------------------------------------------------------
// Weight transpose + fp16 hi/lo split into conv layout (unchanged).
// ---------------------------------------------------------------------------
template<int K3, int NCOG, int NCH>
__global__ __launch_bounds__(256) void wsplit_k(
    const float* __restrict__ w, _Float16* __restrict__ dh, _Float16* __restrict__ dl,
    int CI)
{
    __shared__ float s[32*K3];
    const int co = blockIdx.x, cig = blockIdx.y, t = threadIdx.x;
    const float* src = w + ((size_t)co*CI + cig*32)*K3;
    for (int m = t; m < 32*K3; m += 256) s[m] = src[m];
    __syncthreads();
    const int coG = co >> 6, col = co & 63;
    for (int m = t; m < 32*K3; m += 256) {
        const int tap = m >> 5, cil = m & 31;
        const float x = s[cil*K3 + tap];
        const _Float16 h = (_Float16)x;
        const _Float16 l = (_Float16)(x - (float)h);
        const int b = cil >> 3, jj = cil & 7;
        const int sl = col*4 + b;
        const int p = sl ^ ((sl >> 3) & 7);
        const size_t base = ((size_t)(tap*NCOG + coG)*NCH + cig) * 2048;
        dh[base + p*8 + jj] = h;
        dl[base + p*8 + jj] = l;
    }
}

// ---------------------------------------------------------------------------
// Edge kernel v3 (unchanged from R12 — conflicts 0, absmax 0.0).
// ---------------------------------------------------------------------------
__global__ __launch_bounds__(256, 3) void edge_kernel(
    const int* __restrict__ edge_i,
    const float* __restrict__ a_node, const float* __restrict__ g_vox,
    const float* __restrict__ n_node,
    const _Float16* __restrict__ wemt_h, const _Float16* __restrict__ wemt_l,
    const float* __restrict__ W_mu, const float* __restrict__ b_mu,
    const float* __restrict__ uw2, const float* __restrict__ ub2,
    _Float16* __restrict__ x0h, _Float16* __restrict__ x0l)
{
    __shared__ __align__(16) _Float16 sAh[4096], sAl[4096];
    __shared__ __align__(16) _Float16 sBh[2][4096], sBl[2][4096];
    __shared__ float sV1[64], sV2[64], sRed[4*64];

    const int j = blockIdx.x, t = threadIdx.x;
    const int lane = t & 63, wv = t >> 6, ln15 = lane & 15, kg = lane >> 4;
    const int ebase = j << 8;

    gld16(wemt_h + t*8, &sAh[t*8]);
    gld16(wemt_h + 2048 + t*8, &sAh[2048 + t*8]);
    gld16(wemt_l + t*8, &sAl[t*8]);
    gld16(wemt_l + 2048 + t*8, &sAl[2048 + t*8]);

    const int r = t >> 2, sub = t & 3;
    float4 gv4[4];
    #pragma unroll
    for (int m4 = 0; m4 < 4; m4++)
        gv4[m4] = *(const float4*)&g_vox[j*64 + sub*16 + m4*4];

    float4 A[2][4], N[2][4];
    {
        const int iA = edge_i[ebase + r];
        #pragma unroll
        for (int m4 = 0; m4 < 4; m4++)
            A[0][m4] = *(const float4*)&a_node[(size_t)iA*64 + sub*16 + m4*4];
        #pragma unroll
        for (int eF = 0; eF < 4; eF++) {
            const int ieX = edge_i[ebase + eF*16 + ln15];
            N[0][eF] = *(const float4*)&n_node[(size_t)ieX*64 + wv*16 + kg*4];
        }
    }

    asm volatile("s_waitcnt vmcnt(0)" ::: "memory");
    __syncthreads();

    float psum[4] = {0.f, 0.f, 0.f, 0.f};

    #pragma unroll
    for (int T = 0; T < 4; T++) {
        const int par = T & 1;
        {
            float s1v[16];
            #pragma unroll
            for (int m4 = 0; m4 < 4; m4++) {
                const float4 a = A[par][m4], g = gv4[m4];
                s1v[m4*4 + 0] = silu_f(a.x + g.x);
                s1v[m4*4 + 1] = silu_f(a.y + g.y);
                s1v[m4*4 + 2] = silu_f(a.z + g.z);
                s1v[m4*4 + 3] = silu_f(a.w + g.w);
            }
            uint32_t hw[8], lw[8];
            #pragma unroll
            for (int m = 0; m < 8; m++) {
                const auto hp = __builtin_amdgcn_cvt_pkrtz(s1v[2*m], s1v[2*m + 1]);
                const float h0f = (float)hp[0], h1f = (float)hp[1];
                const auto lp = __builtin_amdgcn_cvt_pkrtz(s1v[2*m] - h0f, s1v[2*m + 1] - h1f);
                hw[m] = __builtin_bit_cast(uint32_t, hp);
                lw[m] = __builtin_bit_cast(uint32_t, lp);
            }
            const int q = sub >> 1, kg0 = (sub & 1) * 2;
            const int sl0 = (q*4 + kg0)*64 + r;
            const int sl1 = sl0 + 64;
            const int p0 = sl0 ^ ((sl0 >> 6) & 7);
            const int p1 = sl1 ^ ((sl1 >> 6) & 7);
            uint4 u;
            u.x = hw[0]; u.y = hw[1]; u.z = hw[2]; u.w = hw[3];
            *(uint4*)&sBh[par][p0*8] = u;
            u.x = hw[4]; u.y = hw[5]; u.z = hw[6]; u.w = hw[7];
            *(uint4*)&sBh[par][p1*8] = u;
            u.x = lw[0]; u.y = lw[1]; u.z = lw[2]; u.w = lw[3];
            *(uint4*)&sBl[par][p0*8] = u;
            u.x = lw[4]; u.y = lw[5]; u.z = lw[6]; u.w = lw[7];
            *(uint4*)&sBl[par][p1*8] = u;
        }
        if (T < 3) {
            const int b1 = ebase + (T + 1)*64;
            const int iA = edge_i[b1 + r];
            #pragma unroll
            for (int m4 = 0; m4 < 4; m4++)
                A[par ^ 1][m4] = *(const float4*)&a_node[(size_t)iA*64 + sub*16 + m4*4];
            #pragma unroll
            for (int eF = 0; eF < 4; eF++) {
                const int ieX = edge_i[b1 + eF*16 + ln15];
                N[par ^ 1][eF] = *(const float4*)&n_node[(size_t)ieX*64 + wv*16 + kg*4];
            }
        }
        __syncthreads();
        #pragma unroll
        for (int eF = 0; eF < 4; eF++) {
            const int e = eF*16 + ln15;
            f32x4 acc;
            {
                const float4 nv = N[par][eF];
                acc[0] = nv.x; acc[1] = nv.y; acc[2] = nv.z; acc[3] = nv.w;
            }
            #pragma unroll
            for (int q2 = 0; q2 < 2; q2++) {
                const int sa = q2*256 + (wv*16 + ln15)*4 + kg;
                const int pa = sa ^ ((sa >> 3) & 7);
                const half8 Ah = *(const half8*)&sAh[pa*8];
                const half8 Al = *(const half8*)&sAl[pa*8];
                const int sbs = (q2*4 + kg)*64 + e;
                const int pb = sbs ^ ((sbs >> 6) & 7);
                const half8 Bh = *(const half8*)&sBh[par][pb*8];
                const half8 Bl = *(const half8*)&sBl[par][pb*8];
                acc = __builtin_amdgcn_mfma_f32_16x16x32_f16(Ah, Bh, acc, 0, 0, 0);
                acc = __builtin_amdgcn_mfma_f32_16x16x32_f16(Ah, Bl, acc, 0, 0, 0);
                acc = __builtin_amdgcn_mfma_f32_16x16x32_f16(Al, Bh, acc, 0, 0, 0);
            }
            #pragma unroll
            for (int rg = 0; rg < 4; rg++) psum[rg] += silu_f(acc[rg]);
        }
    }

    #pragma unroll
    for (int rg = 0; rg < 4; rg++) {
        float v = psum[rg];
        v += __shfl_xor(v, 1, 64); v += __shfl_xor(v, 2, 64);
        v += __shfl_xor(v, 4, 64); v += __shfl_xor(v, 8, 64);
        psum[rg] = v;
    }
    __syncthreads();
    if (ln15 == 0) {
        #pragma unroll
        for (int rg = 0; rg < 4; rg++)
            sV1[wv*16 + kg*4 + rg] = psum[rg] * (1.0f / 256.0f);
    }
    __syncthreads();
    {
        const int c = t & 63, part = t >> 6;
        float h = (part == 0) ? b_mu[c] : 0.f;
        #pragma unroll
        for (int k2 = 0; k2 < 16; k2++) {
            const int k = part*16 + k2;
            h = fmaf(sV1[k], W_mu[k*64 + c], h);
        }
        sRed[part*64 + c] = h;
    }
    __syncthreads();
    if (t < 64)
        sV2[t] = silu_f(sRed[t] + sRed[64 + t] + sRed[128 + t] + sRed[192 + t]);
    __syncthreads();
    {
        const int c = t & 63, part = t >> 6;
        float g = (part == 0) ? ub2[c] : 0.f;
        #pragma unroll
        for (int k2 = 0; k2 < 16; k2++) {
            const int k = part*16 + k2;
            g = fmaf(sV2[k], uw2[k*64 + c], g);
        }
        sRed[part*64 + c] = g;
    }
    __syncthreads();
    if (t < 64) {
        const float val = (sRed[t] + sRed[64 + t] + sRed[128 + t] + sRed[192 + t]) * BN_S;
        const _Float16 hh = (_Float16)val;
        const _Float16 ll = (_Float16)(val - (float)hh);
        const int c = t, zz = j >> 8, v = j & 255;
        const int oct = (c >> 3) & 3;
        const int vsw = v ^ (oct << 1);
        const size_t a16 = ((size_t)((c >> 5)*16 + zz)*1024 + oct*256 + vsw)*8 + (c & 7);
        x0h[a16] = hh; x0l[a16] = ll;
    }
}

// ---------------------------------------------------------------------------
// Conv3D via MFMA shift-GEMM v8 + optional XCD-group swizzle (SWZ):
// logical blocks (d0, coG, z) with the same (coG, z) — sharing the weight
// panel and overlapping X planes — are grouped onto ONE XCD so they hit its
// private L2 instead of re-fetching from HBM. Bijective when
// (gridDim.y*gridDim.z) % 8 == 0. Conv body identical to R12 (VGPR-clean).
// ---------------------------------------------------------------------------
template<int KK, int CI, int NCO32, int CIS, bool SWZ>
__global__ __launch_bounds__(256, 4) void conv_mfma_k(
    const _Float16* __restrict__ xh, const _Float16* __restrict__ xl,
    const _Float16* __restrict__ wh, const _Float16* __restrict__ wl,
    float* __restrict__ slab)
{
    constexpr int P = KK/2, K2 = KK*KK, NCH = CI/32, NCHS = NCH/CIS;
    constexpr int CO = NCO32*32, NCOG64 = NCO32/2;

    int d0, coG32, zidx;
    if (SWZ) {
        // hardware linear id -> logical (group-per-XCD) id
        const int lin = blockIdx.x + 16*(blockIdx.y + NCO32*blockIdx.z);
        const int xcd = lin & 7, rest = lin >> 3;
        const int i = rest & 15, gg = rest >> 4;
        const int g = gg*8 + xcd;
        d0 = i; coG32 = g % NCO32; zidx = g / NCO32;
    } else {
        d0 = blockIdx.x; coG32 = blockIdx.y; zidx = blockIdx.z;
    }
    const int co64G = coG32 >> 1, coHalf = coG32 & 1;
    const int cis = zidx / KK, kd = zidx % KK;
    const int t = threadIdx.x;
    const int lane = t & 63, wv = t >> 6;
    const int ln15 = lane & 15, kg = lane >> 4;

    float* sout = slab + ((size_t)zidx*CO + coG32*32)*4096 + d0*256;
    const int z = d0 + kd - P;
    if ((unsigned)z >= 16u) {   // OOB depth plane -> zero partial
        for (int m = t; m < 32*256; m += 256)
            sout[(size_t)(m >> 8)*4096 + (m & 255)] = 0.f;
        return;
    }

    __shared__ __align__(16) _Float16 sXh[8192];   // 16 KB
    __shared__ __align__(16) _Float16 sXl[8192];   // 16 KB
    __shared__ __align__(16) _Float16 zb[8];
    if (t < 8) zb[t] = (_Float16)0.f;

    int aoff[2];
    #pragma unroll
    for (int cf = 0; cf < 2; cf++) {
        const int s = (coHalf*32 + cf*16 + ln15)*4 + kg;
        aoff[cf] = (s ^ ((s >> 3) & 7)) * 8;
    }

    auto stage_X = [&](int ch) {
        const size_t b16 = ((size_t)ch*16 + z) * 8192;
        #pragma unroll
        for (int q = 0; q < 4; q++) {
            gld16(xh + b16 + (q*256 + t)*8, &sXh[(q*256 + t)*8]);
            gld16(xl + b16 + (q*256 + t)*8, &sXl[(q*256 + t)*8]);
        }
    };
    auto loadA = [&](int ch, int t2, half8* Ah, half8* Al) {
        const size_t b = ((size_t)((kd*K2 + t2)*NCOG64 + co64G)*NCH + ch) * 2048;
        #pragma unroll
        for (int cf = 0; cf < 2; cf++) {
            Ah[cf] = *(const half8*)&wh[b + aoff[cf]];
            Al[cf] = *(const half8*)&wl[b + aoff[cf]];
        }
    };

    f32x4 acc[2][4];
    #pragma unroll
    for (int a = 0; a < 2; a++)
        #pragma unroll
        for (int b = 0; b < 4; b++)
            #pragma unroll
            for (int r2 = 0; r2 < 4; r2++) acc[a][b][r2] = 0.f;

    const int ch0 = cis * NCHS;
    half8 nAh[2], nAl[2];
    stage_X(ch0);
    loadA(ch0, 0, nAh, nAl);
    asm volatile("s_waitcnt vmcnt(0)" ::: "memory");
    __syncthreads();

    for (int cc = 0; cc < NCHS; cc++) {
        const int ch = ch0 + cc;
        for (int t2 = 0; t2 < K2; t2++) {
            half8 cAh[2], cAl[2];
            #pragma unroll
            for (int cf = 0; cf < 2; cf++) { cAh[cf] = nAh[cf]; cAl[cf] = nAl[cf]; }
            if (t2 + 1 < K2)          loadA(ch, t2 + 1, nAh, nAl);
            else if (cc + 1 < NCHS)   loadA(ch + 1, 0, nAh, nAl);

            const int kh = t2 / KK, kw = t2 % KK;
            __builtin_amdgcn_s_setprio(1);
            #pragma unroll
            for (int f = 0; f < 4; f++) {
                const int h_in = wv*4 + f + kh - P;
                if ((unsigned)h_in < 16u) {
                    const int w_in = ln15 + kw - P;
                    const bool ok = (unsigned)w_in < 16u;
                    const int slot = ok ? (kg*256 + h_in*16 + (w_in ^ (kg << 1))) : 0;
                    const half8 Bh = ok ? *(const half8*)&sXh[slot*8] : *(const half8*)zb;
                    const half8 Bl = ok ? *(const half8*)&sXl[slot*8] : *(const half8*)zb;
                    #pragma unroll
                    for (int cf = 0; cf < 2; cf++) {
                        acc[cf][f] = __builtin_amdgcn_mfma_f32_16x16x32_f16(cAh[cf], Bh, acc[cf][f], 0, 0, 0);
                        acc[cf][f] = __builtin_amdgcn_mfma_f32_16x16x32_f16(cAh[cf], Bl, acc[cf][f], 0, 0, 0);
                        acc[cf][f] = __builtin_amdgcn_mfma_f32_16x16x32_f16(cAl[cf], Bh, acc[cf][f], 0, 0, 0);
                    }
                }
            }
            __builtin_amdgcn_s_setprio(0);
        }
        if (cc + 1 < NCHS) {
            __syncthreads();                               // all reads of sX done
            stage_X(ch + 1);
            asm volatile("s_waitcnt vmcnt(0)" ::: "memory");
            __syncthreads();                               // new chunk landed
        }
    }

    #pragma unroll
    for (int cf = 0; cf < 2; cf++)
        #pragma unroll
        for (int f = 0; f < 4; f++)
            #pragma unroll
            for (int r2 = 0; r2 < 4; r2++)
                sout[(size_t)(cf*16 + kg*4 + r2)*4096 + wv*64 + f*16 + ln15] = acc[cf][f][r2];
}

// ---------------------------------------------------------------------------
// Reduce S kd/cis-slabs + BN (+residual) (+relu); emit fp32 / fp16-split /
// poolmax partials. grid(16 z, CO/8). OUT=1 applies the kg-XOR vox swizzle.
// ---------------------------------------------------------------------------
template<int S, int RMODE, int OUT>
__global__ __launch_bounds__(256) void reduce_k(
    const float* __restrict__ pbuf, const float* __restrict__ addsrc,
    float* __restrict__ outf, _Float16* __restrict__ oh, _Float16* __restrict__ ol,
    int CO)
{
    const int z = blockIdx.x, c8 = blockIdx.y, v = threadIdx.x;
    float val[8];
    #pragma unroll
    for (int jj = 0; jj < 8; jj++) {
        const int c = c8*8 + jj;
        float a = 0.f;
        #pragma unroll
        for (int s = 0; s < S; s++)
            a += pbuf[((size_t)s*CO + c)*4096 + z*256 + v];
        a *= BN_S;
        if (RMODE == 3) a += addsrc[(size_t)c*4096 + z*256 + v];
        if (RMODE != 2) a = fmaxf(a, 0.f);
        val[jj] = a;
    }
    if (OUT == 0) {
        #pragma unroll
        for (int jj = 0; jj < 8; jj++)
            outf[(size_t)(c8*8 + jj)*4096 + z*256 + v] = val[jj];
    } else if (OUT == 1) {
        half8 hv, lv;
        #pragma unroll
        for (int jj = 0; jj < 8; jj++) {
            hv[jj] = (_Float16)val[jj];
            lv[jj] = (_Float16)(val[jj] - (float)hv[jj]);
        }
        const int oct = c8 & 3;
        const int vsw = v ^ (oct << 1);
        const size_t a16 = ((size_t)((c8 >> 2)*16 + z)*1024 + oct*256 + vsw)*8;
        *(half8*)&oh[a16] = hv;
        *(half8*)&ol[a16] = lv;
    } else {
        __shared__ float sm[4][8];
        #pragma unroll
        for (int jj = 0; jj < 8; jj++) {
            float m = val[jj];
            m = fmaxf(m, __shfl_xor(m, 1, 64));  m = fmaxf(m, __shfl_xor(m, 2, 64));
            m = fmaxf(m, __shfl_xor(m, 4, 64));  m = fmaxf(m, __shfl_xor(m, 8, 64));
            m = fmaxf(m, __shfl_xor(m, 16, 64)); m = fmaxf(m, __shfl_xor(m, 32, 64));
            if ((v & 63) == 0) sm[v >> 6][jj] = m;
        }
        __syncthreads();
        if (v < 8) {
            const float m = fmaxf(fmaxf(sm[0][v], sm[1][v]), fmaxf(sm[2][v], sm[3][v]));
            outf[z*CO + c8*8 + v] = m;
        }
    }
}

// ---------------------------------------------------------------------------
__global__ __launch_bounds__(256) void fc_k(
    const float* __restrict__ pp, const float* __restrict__ fcw,
    const float* __restrict__ fcb, float* __restrict__ out)
{
    __shared__ float sp[256];
    const int t = threadIdx.x;
    float m = pp[t];
    for (int zz = 1; zz < 16; zz++) m = fmaxf(m, pp[zz*256 + t]);
    sp[t] = m;
    __syncthreads();
    if (t < 20) {
        float s = fcb[t];
        for (int c = 0; c < 256; c++) s = fmaf(sp[c], fcw[c*20 + t], s);
        out[t] = s;
    }
}

// ---------------------------------------------------------------------------
extern "C" void kernel_launch(void* const* d_in, const int* in_sizes, int n_in,
                              void* d_out, int out_size, void* d_ws, size_t ws_size,
                              hipStream_t stream)
{
    const float* node_embedding = (const float*)d_in[0];
    const float* node_pos       = (const float*)d_in[1];
    const float* grid_pos       = (const float*)d_in[2];
    const int*   edge_index     = (const int*)d_in[3];
    const float* ew1 = (const float*)d_in[4];
    const float* eb1 = (const float*)d_in[5];
    const float* ew2 = (const float*)d_in[6];
    const float* eb2 = (const float*)d_in[7];
    const float* mw1 = (const float*)d_in[8];
    const float* mb1 = (const float*)d_in[9];
    const float* mw2 = (const float*)d_in[10];
    const float* mb2 = (const float*)d_in[11];
    const float* uw1 = (const float*)d_in[12];
    const float* ub1 = (const float*)d_in[13];
    const float* uw2 = (const float*)d_in[14];
    const float* ub2 = (const float*)d_in[15];
    const float* c1a = (const float*)d_in[16];
    const float* c1b = (const float*)d_in[17];
    const float* c1s = (const float*)d_in[18];
    const float* c2a = (const float*)d_in[19];
    const float* c2b = (const float*)d_in[20];
    const float* c2s = (const float*)d_in[21];
    const float* c3a = (const float*)d_in[22];
    const float* c3b = (const float*)d_in[23];
    const float* c3s = (const float*)d_in[24];
    const float* fcw = (const float*)d_in[25];
    const float* fcb = (const float*)d_in[26];
    float* out = (float*)d_out;
    const int* edge_i = edge_index;   // row 0

    float* ws = (float*)d_ws;
    float* a_node = ws;                ws += 262144;
    float* g_vox  = ws;                ws += 262144;
    float* n_node = ws;                ws += 262144;
    float* W_mu   = ws;                ws += 4096;
    float* b_mu   = ws;                ws += 64;
    _Float16* wemt_h = (_Float16*)ws;  ws += 2048;
    _Float16* wemt_l = (_Float16*)ws;  ws += 2048;
    _Float16* x0h = (_Float16*)ws;     ws += 131072;
    _Float16* x0l = (_Float16*)ws;     ws += 131072;
    _Float16* t2h = (_Float16*)ws;     ws += 262144;
    _Float16* t2l = (_Float16*)ws;     ws += 262144;
    _Float16* x2h = (_Float16*)ws;     ws += 262144;
    _Float16* x2l = (_Float16*)ws;     ws += 262144;
    _Float16* t3h = (_Float16*)ws;     ws += 524288;
    _Float16* t3l = (_Float16*)ws;     ws += 524288;
    float* u2 = ws;                    ws += 524288;
    float* u3 = ws;                    ws += 1048576;
    float* slab = ws;                  ws += 5242880;
    float* poolPart = ws;              ws += 4096;
    _Float16* wh = (_Float16*)ws;      ws += 4585472;   // 9170944 f16
    _Float16* wl = (_Float16*)ws;      ws += 4585472;
    // aliases valid after edge_kernel (node tables dead):
    _Float16* t1h = (_Float16*)a_node;
    _Float16* t1l = (_Float16*)(a_node + 131072);
    float* u1 = g_vox;
    _Float16* x1h = (_Float16*)n_node;
    _Float16* x1l = (_Float16*)(n_node + 131072);

    _Float16* w1a_h = wh + 0;       _Float16* w1a_l = wl + 0;
    _Float16* w1b_h = wh + 110592;  _Float16* w1b_l = wl + 110592;
    _Float16* w1s_h = wh + 221184;  _Float16* w1s_l = wl + 221184;
    _Float16* w2a_h = wh + 733184;  _Float16* w2a_l = wl + 733184;
    _Float16* w2b_h = wh + 954368;  _Float16* w2b_l = wl + 954368;
    _Float16* w2s_h = wh + 1396736; _Float16* w2s_l = wl + 1396736;
    _Float16* w3a_h = wh + 2420736; _Float16* w3a_l = wl + 2420736;
    _Float16* w3b_h = wh + 3305472; _Float16* w3b_l = wl + 3305472;
    _Float16* w3s_h = wh + 5074944; _Float16* w3s_l = wl + 5074944;

    // ---- weight transpose + split ----
    hipLaunchKernelGGL((wsplit_k<27,1,2>),  dim3(64,2),  dim3(256), 0, stream, c1a, w1a_h, w1a_l, 64);
    hipLaunchKernelGGL((wsplit_k<27,1,2>),  dim3(64,2),  dim3(256), 0, stream, c1b, w1b_h, w1b_l, 64);
    hipLaunchKernelGGL((wsplit_k<125,1,2>), dim3(64,2),  dim3(256), 0, stream, c1s, w1s_h, w1s_l, 64);
    hipLaunchKernelGGL((wsplit_k<27,2,2>),  dim3(128,2), dim3(256), 0, stream, c2a, w2a_h, w2a_l, 64);
    hipLaunchKernelGGL((wsplit_k<27,2,4>),  dim3(128,4), dim3(256), 0, stream, c2b, w2b_h, w2b_l, 128);
    hipLaunchKernelGGL((wsplit_k<125,2,2>), dim3(128,2), dim3(256), 0, stream, c2s, w2s_h, w2s_l, 64);
    hipLaunchKernelGGL((wsplit_k<27,4,4>),  dim3(256,4), dim3(256), 0, stream, c3a, w3a_h, w3a_l, 128);
    hipLaunchKernelGGL((wsplit_k<27,4,8>),  dim3(256,8), dim3(256), 0, stream, c3b, w3b_h, w3b_l, 256);
    hipLaunchKernelGGL((wsplit_k<125,4,4>), dim3(256,4), dim3(256), 0, stream, c3s, w3s_h, w3s_l, 128);

    // ---- MPNN ----
    hipLaunchKernelGGL(prep_w_k, dim3(64), dim3(64), 0, stream,
                       ew2, mw1, mw2, uw1, mb2, ub1, W_mu, b_mu, wemt_h, wemt_l);
    hipLaunchKernelGGL(prep_nodes_k, dim3(4096), dim3(64), 0, stream,
                       node_embedding, node_pos, grid_pos, ew1, eb1, mw1, mb1, eb2,
                       a_node, g_vox, n_node);
    hipLaunchKernelGGL(edge_kernel, dim3(4096), dim3(256), 0, stream,
                       edge_i, a_node, g_vox, n_node, wemt_h, wemt_l,
                       W_mu, b_mu, uw2, ub2, x0h, x0l);

    // ---- ResNet3D ----
    // Block 1: 64 -> 64  (groups = 2*6 = 12, not %8 -> no swizzle)
    hipLaunchKernelGGL((conv_mfma_k<3,64,2,2,false>), dim3(16,2,6), dim3(256), 0, stream, x0h, x0l, w1a_h, w1a_l, slab);
    hipLaunchKernelGGL((reduce_k<6,1,1>), dim3(16,8), dim3(256), 0, stream, slab, (const float*)nullptr, (float*)nullptr, t1h, t1l, 64);
    hipLaunchKernelGGL((conv_mfma_k<3,64,2,2,false>), dim3(16,2,6), dim3(256), 0, stream, t1h, t1l, w1b_h, w1b_l, slab);
    hipLaunchKernelGGL((reduce_k<6,2,0>), dim3(16,8), dim3(256), 0, stream, slab, (const float*)nullptr, u1, (_Float16*)nullptr, (_Float16*)nullptr, 64);
    hipLaunchKernelGGL((conv_mfma_k<5,64,2,2,false>), dim3(16,2,10), dim3(256), 0, stream, x0h, x0l, w1s_h, w1s_l, slab);
    hipLaunchKernelGGL((reduce_k<10,3,1>), dim3(16,8), dim3(256), 0, stream, slab, u1, (float*)nullptr, x1h, x1l, 64);
    // Block 2: 64 -> 128  (groups 24/24/40 -> swizzle)
    hipLaunchKernelGGL((conv_mfma_k<3,64,4,2,true>), dim3(16,4,6), dim3(256), 0, stream, x1h, x1l, w2a_h, w2a_l, slab);
    hipLaunchKernelGGL((reduce_k<6,1,1>), dim3(16,16), dim3(256), 0, stream, slab, (const float*)nullptr, (float*)nullptr, t2h, t2l, 128);
    hipLaunchKernelGGL((conv_mfma_k<3,128,4,2,true>), dim3(16,4,6), dim3(256), 0, stream, t2h, t2l, w2b_h, w2b_l, slab);
    hipLaunchKernelGGL((reduce_k<6,2,0>), dim3(16,16), dim3(256), 0, stream, slab, (const float*)nullptr, u2, (_Float16*)nullptr, (_Float16*)nullptr, 128);
    hipLaunchKernelGGL((conv_mfma_k<5,64,4,2,true>), dim3(16,4,10), dim3(256), 0, stream, x1h, x1l, w2s_h, w2s_l, slab);
    hipLaunchKernelGGL((reduce_k<10,3,1>), dim3(16,16), dim3(256), 0, stream, slab, u2, (float*)nullptr, x2h, x2l, 128);
    // Block 3: 128 -> 256  (groups 24/24/40 -> swizzle)
    hipLaunchKernelGGL((conv_mfma_k<3,128,8,1,true>), dim3(16,8,3), dim3(256), 0, stream, x2h, x2l, w3a_h, w3a_l, slab);
    hipLaunchKernelGGL((reduce_k<3,1,1>), dim3(16,32), dim3(256), 0, stream, slab, (const float*)nullptr, (float*)nullptr, t3h, t3l, 256);
    hipLaunchKernelGGL((conv_mfma_k<3,256,8,1,true>), dim3(16,8,3), dim3(256), 0, stream, t3h, t3l, w3b_h, w3b_l, slab);
    hipLaunchKernelGGL((reduce_k<3,2,0>), dim3(16,32), dim3(256), 0, stream, slab, (const float*)nullptr, u3, (_Float16*)nullptr, (_Float16*)nullptr, 256);
    hipLaunchKernelGGL((conv_mfma_k<5,128,8,1,true>), dim3(16,8,5), dim3(256), 0, stream, x2h, x2l, w3s_h, w3s_l, slab);
    hipLaunchKernelGGL((reduce_k<5,3,2>), dim3(16,32), dim3(256), 0, stream, slab, u3, poolPart, (_Float16*)nullptr, (_Float16*)nullptr, 256);

    hipLaunchKernelGGL(fc_k, dim3(1), dim3(256), 0, stream, poolPart, fcw, fcb, out);

    (void)in_sizes; (void)n_in; (void)out_size; (void)ws_size;
}

// Round 15
// 477.476 us; speedup vs baseline: 1.2421x; 1.1271x over previous
//
#include <hip/hip_runtime.h>
#include <math.h>

// eval-mode BatchNorm3d scale: np.float32(1/sqrt(1+1e-5))
#define BN_S 0.9999950000374997f

typedef _Float16 half8 __attribute__((ext_vector_type(8)));
typedef float f32x4 __attribute__((ext_vector_type(4)));

__device__ __forceinline__ float silu_f(float x) {
    return __fdividef(x, 1.0f + __expf(-x));
}

// global -> LDS async DMA, 16B per lane (lane-linear LDS destination)
__device__ __forceinline__ void gld16(const void* g, void* l) {
    __builtin_amdgcn_global_load_lds(
        (const __attribute__((address_space(1))) void*)g,
        (__attribute__((address_space(3))) void*)l, 16, 0, 0);
}

// ---------------------------------------------------------------------------
// Merged prep: blocks 0..4095 build per-node/per-voxel tables; blocks <64
// additionally build W_mu, b_mu, W_em^T (split+swizzled).
// ---------------------------------------------------------------------------
__global__ __launch_bounds__(64) void prep_all_k(
    const float* __restrict__ node_embedding, const float* __restrict__ node_pos,
    const float* __restrict__ grid_pos, const float* __restrict__ ew1,
    const float* __restrict__ eb1, const float* __restrict__ mw1,
    const float* __restrict__ mb1, const float* __restrict__ eb2,
    const float* __restrict__ ew2, const float* __restrict__ mw2,
    const float* __restrict__ uw1, const float* __restrict__ mb2,
    const float* __restrict__ ub1,
    float* __restrict__ a_node, float* __restrict__ g_vox, float* __restrict__ n_node,
    float* __restrict__ W_mu, float* __restrict__ b_mu,
    _Float16* __restrict__ wemt_h, _Float16* __restrict__ wemt_l)
{
    const int v = blockIdx.x, c = threadIdx.x;
    if (v < 64) {
        const int k = v;
        float s = 0.f;
        for (int m = 0; m < 64; m++) s = fmaf(ew2[k*64 + m], mw1[(64 + m)*64 + c], s);
        {
            const int q = k >> 5, kg = (k >> 3) & 3, jj = k & 7;
            const int sl = q*256 + c*4 + kg;
            const int p = sl ^ ((sl >> 3) & 7);
            const _Float16 h = (_Float16)s;
            const _Float16 l = (_Float16)(s - (float)h);
            wemt_h[p*8 + jj] = h;
            wemt_l[p*8 + jj] = l;
        }
        float s2 = 0.f;
        for (int m = 0; m < 64; m++) s2 = fmaf(mw2[k*64 + m], uw1[m*64 + c], s2);
        W_mu[k*64 + c] = s2;
        if (k == 0) {
            float s3 = ub1[c];
            for (int m = 0; m < 64; m++) s3 = fmaf(mb2[m], uw1[m*64 + c], s3);
            b_mu[c] = s3;
        }
    }
    const float p0 = node_pos[v*3], p1 = node_pos[v*3 + 1], p2 = node_pos[v*3 + 2];
    a_node[v*64 + c] = fmaf(p0, ew1[c], fmaf(p1, ew1[64 + c], fmaf(p2, ew1[128 + c], eb1[c])));
    const float q0 = grid_pos[v*3], q1 = grid_pos[v*3 + 1], q2 = grid_pos[v*3 + 2];
    g_vox[v*64 + c] = fmaf(q0, ew1[192 + c], fmaf(q1, ew1[256 + c], q2 * ew1[320 + c]));
    float s = mb1[c];
    for (int k = 0; k < 64; k++) s = fmaf(node_embedding[v*64 + k], mw1[k*64 + c], s);
    for (int k = 0; k < 64; k++) s = fmaf(eb2[k], mw1[(64 + k)*64 + c], s);
    n_node[v*64 + c] = s;
}

// ---------------------------------------------------------------------------
// Merged weight transpose + fp16 hi/lo split: one kernel per K3 class,
// flat block id -> (conv idx, co, cig) via descriptor struct.
// ---------------------------------------------------------------------------
struct WSArgs {
    const float* src[6];
    _Float16* dh[6];
    _Float16* dl[6];
    int CI[6], NCOG[6], NCH[6];
    int ofs[7];
    int n;
};

template<int K3>
__global__ __launch_bounds__(256) void wsplit_k(WSArgs a)
{
    __shared__ float s[32*K3];
    const int flat = blockIdx.x, t = threadIdx.x;
    int i = 0;
    while (i + 1 < a.n && flat >= a.ofs[i + 1]) i++;
    const int local = flat - a.ofs[i];
    const int NCH = a.NCH[i], NCOG = a.NCOG[i], CI = a.CI[i];
    const int co = local / NCH, cig = local % NCH;
    const float* src = a.src[i] + ((size_t)co*CI + cig*32)*K3;
    for (int m = t; m < 32*K3; m += 256) s[m] = src[m];
    __syncthreads();
    const int coG = co >> 6, col = co & 63;
    _Float16* dh = a.dh[i];
    _Float16* dl = a.dl[i];
    for (int m = t; m < 32*K3; m += 256) {
        const int tap = m >> 5, cil = m & 31;
        const float x = s[cil*K3 + tap];
        const _Float16 h = (_Float16)x;
        const _Float16 l = (_Float16)(x - (float)h);
        const int b = cil >> 3, jj = cil & 7;
        const int sl = col*4 + b;
        const int p = sl ^ ((sl >> 3) & 7);
        const size_t base = ((size_t)(tap*NCOG + coG)*NCH + cig) * 2048;
        dh[base + p*8 + jj] = h;
        dl[base + p*8 + jj] = l;
    }
}

// ---------------------------------------------------------------------------
// Edge kernel v3 (unchanged from R14 — conflicts 0, absmax 0.0).
// ---------------------------------------------------------------------------
__global__ __launch_bounds__(256, 3) void edge_kernel(
    const int* __restrict__ edge_i,
    const float* __restrict__ a_node, const float* __restrict__ g_vox,
    const float* __restrict__ n_node,
    const _Float16* __restrict__ wemt_h, const _Float16* __restrict__ wemt_l,
    const float* __restrict__ W_mu, const float* __restrict__ b_mu,
    const float* __restrict__ uw2, const float* __restrict__ ub2,
    _Float16* __restrict__ x0h, _Float16* __restrict__ x0l)
{
    __shared__ __align__(16) _Float16 sAh[4096], sAl[4096];
    __shared__ __align__(16) _Float16 sBh[2][4096], sBl[2][4096];
    __shared__ float sV1[64], sV2[64], sRed[4*64];

    const int j = blockIdx.x, t = threadIdx.x;
    const int lane = t & 63, wv = t >> 6, ln15 = lane & 15, kg = lane >> 4;
    const int ebase = j << 8;

    gld16(wemt_h + t*8, &sAh[t*8]);
    gld16(wemt_h + 2048 + t*8, &sAh[2048 + t*8]);
    gld16(wemt_l + t*8, &sAl[t*8]);
    gld16(wemt_l + 2048 + t*8, &sAl[2048 + t*8]);

    const int r = t >> 2, sub = t & 3;
    float4 gv4[4];
    #pragma unroll
    for (int m4 = 0; m4 < 4; m4++)
        gv4[m4] = *(const float4*)&g_vox[j*64 + sub*16 + m4*4];

    float4 A[2][4], N[2][4];
    {
        const int iA = edge_i[ebase + r];
        #pragma unroll
        for (int m4 = 0; m4 < 4; m4++)
            A[0][m4] = *(const float4*)&a_node[(size_t)iA*64 + sub*16 + m4*4];
        #pragma unroll
        for (int eF = 0; eF < 4; eF++) {
            const int ieX = edge_i[ebase + eF*16 + ln15];
            N[0][eF] = *(const float4*)&n_node[(size_t)ieX*64 + wv*16 + kg*4];
        }
    }

    asm volatile("s_waitcnt vmcnt(0)" ::: "memory");
    __syncthreads();

    float psum[4] = {0.f, 0.f, 0.f, 0.f};

    #pragma unroll
    for (int T = 0; T < 4; T++) {
        const int par = T & 1;
        {
            float s1v[16];
            #pragma unroll
            for (int m4 = 0; m4 < 4; m4++) {
                const float4 a = A[par][m4], g = gv4[m4];
                s1v[m4*4 + 0] = silu_f(a.x + g.x);
                s1v[m4*4 + 1] = silu_f(a.y + g.y);
                s1v[m4*4 + 2] = silu_f(a.z + g.z);
                s1v[m4*4 + 3] = silu_f(a.w + g.w);
            }
            uint32_t hw[8], lw[8];
            #pragma unroll
            for (int m = 0; m < 8; m++) {
                const auto hp = __builtin_amdgcn_cvt_pkrtz(s1v[2*m], s1v[2*m + 1]);
                const float h0f = (float)hp[0], h1f = (float)hp[1];
                const auto lp = __builtin_amdgcn_cvt_pkrtz(s1v[2*m] - h0f, s1v[2*m + 1] - h1f);
                hw[m] = __builtin_bit_cast(uint32_t, hp);
                lw[m] = __builtin_bit_cast(uint32_t, lp);
            }
            const int q = sub >> 1, kg0 = (sub & 1) * 2;
            const int sl0 = (q*4 + kg0)*64 + r;
            const int sl1 = sl0 + 64;
            const int p0 = sl0 ^ ((sl0 >> 6) & 7);
            const int p1 = sl1 ^ ((sl1 >> 6) & 7);
            uint4 u;
            u.x = hw[0]; u.y = hw[1]; u.z = hw[2]; u.w = hw[3];
            *(uint4*)&sBh[par][p0*8] = u;
            u.x = hw[4]; u.y = hw[5]; u.z = hw[6]; u.w = hw[7];
            *(uint4*)&sBh[par][p1*8] = u;
            u.x = lw[0]; u.y = lw[1]; u.z = lw[2]; u.w = lw[3];
            *(uint4*)&sBl[par][p0*8] = u;
            u.x = lw[4]; u.y = lw[5]; u.z = lw[6]; u.w = lw[7];
            *(uint4*)&sBl[par][p1*8] = u;
        }
        if (T < 3) {
            const int b1 = ebase + (T + 1)*64;
            const int iA = edge_i[b1 + r];
            #pragma unroll
            for (int m4 = 0; m4 < 4; m4++)
                A[par ^ 1][m4] = *(const float4*)&a_node[(size_t)iA*64 + sub*16 + m4*4];
            #pragma unroll
            for (int eF = 0; eF < 4; eF++) {
                const int ieX = edge_i[b1 + eF*16 + ln15];
                N[par ^ 1][eF] = *(const float4*)&n_node[(size_t)ieX*64 + wv*16 + kg*4];
            }
        }
        __syncthreads();
        #pragma unroll
        for (int eF = 0; eF < 4; eF++) {
            const int e = eF*16 + ln15;
            f32x4 acc;
            {
                const float4 nv = N[par][eF];
                acc[0] = nv.x; acc[1] = nv.y; acc[2] = nv.z; acc[3] = nv.w;
            }
            #pragma unroll
            for (int q2 = 0; q2 < 2; q2++) {
                const int sa = q2*256 + (wv*16 + ln15)*4 + kg;
                const int pa = sa ^ ((sa >> 3) & 7);
                const half8 Ah = *(const half8*)&sAh[pa*8];
                const half8 Al = *(const half8*)&sAl[pa*8];
                const int sbs = (q2*4 + kg)*64 + e;
                const int pb = sbs ^ ((sbs >> 6) & 7);
                const half8 Bh = *(const half8*)&sBh[par][pb*8];
                const half8 Bl = *(const half8*)&sBl[par][pb*8];
                acc = __builtin_amdgcn_mfma_f32_16x16x32_f16(Ah, Bh, acc, 0, 0, 0);
                acc = __builtin_amdgcn_mfma_f32_16x16x32_f16(Ah, Bl, acc, 0, 0, 0);
                acc = __builtin_amdgcn_mfma_f32_16x16x32_f16(Al, Bh, acc, 0, 0, 0);
            }
            #pragma unroll
            for (int rg = 0; rg < 4; rg++) psum[rg] += silu_f(acc[rg]);
        }
    }

    #pragma unroll
    for (int rg = 0; rg < 4; rg++) {
        float v = psum[rg];
        v += __shfl_xor(v, 1, 64); v += __shfl_xor(v, 2, 64);
        v += __shfl_xor(v, 4, 64); v += __shfl_xor(v, 8, 64);
        psum[rg] = v;
    }
    __syncthreads();
    if (ln15 == 0) {
        #pragma unroll
        for (int rg = 0; rg < 4; rg++)
            sV1[wv*16 + kg*4 + rg] = psum[rg] * (1.0f / 256.0f);
    }
    __syncthreads();
    {
        const int c = t & 63, part = t >> 6;
        float h = (part == 0) ? b_mu[c] : 0.f;
        #pragma unroll
        for (int k2 = 0; k2 < 16; k2++) {
            const int k = part*16 + k2;
            h = fmaf(sV1[k], W_mu[k*64 + c], h);
        }
        sRed[part*64 + c] = h;
    }
    __syncthreads();
    if (t < 64)
        sV2[t] = silu_f(sRed[t] + sRed[64 + t] + sRed[128 + t] + sRed[192 + t]);
    __syncthreads();
    {
        const int c = t & 63, part = t >> 6;
        float g = (part == 0) ? ub2[c] : 0.f;
        #pragma unroll
        for (int k2 = 0; k2 < 16; k2++) {
            const int k = part*16 + k2;
            g = fmaf(sV2[k], uw2[k*64 + c], g);
        }
        sRed[part*64 + c] = g;
    }
    __syncthreads();
    if (t < 64) {
        const float val = (sRed[t] + sRed[64 + t] + sRed[128 + t] + sRed[192 + t]) * BN_S;
        const _Float16 hh = (_Float16)val;
        const _Float16 ll = (_Float16)(val - (float)hh);
        const int c = t, zz = j >> 8, v = j & 255;
        const int oct = (c >> 3) & 3;
        const int vsw = v ^ (oct << 1);
        const size_t a16 = ((size_t)((c >> 5)*16 + zz)*1024 + oct*256 + vsw)*8 + (c & 7);
        x0h[a16] = hh; x0l[a16] = ll;
    }
}

// ---------------------------------------------------------------------------
// Conv3D via MFMA shift-GEMM v8 + XCD-group swizzle (unchanged from R14).
// ---------------------------------------------------------------------------
template<int KK, int CI, int NCO32, int CIS, bool SWZ>
__global__ __launch_bounds__(256, 4) void conv_mfma_k(
    const _Float16* __restrict__ xh, const _Float16* __restrict__ xl,
    const _Float16* __restrict__ wh, const _Float16* __restrict__ wl,
    float* __restrict__ slab)
{
    constexpr int P = KK/2, K2 = KK*KK, NCH = CI/32, NCHS = NCH/CIS;
    constexpr int CO = NCO32*32, NCOG64 = NCO32/2;

    int d0, coG32, zidx;
    if (SWZ) {
        const int lin = blockIdx.x + 16*(blockIdx.y + NCO32*blockIdx.z);
        const int xcd = lin & 7, rest = lin >> 3;
        const int i = rest & 15, gg = rest >> 4;
        const int g = gg*8 + xcd;
        d0 = i; coG32 = g % NCO32; zidx = g / NCO32;
    } else {
        d0 = blockIdx.x; coG32 = blockIdx.y; zidx = blockIdx.z;
    }
    const int co64G = coG32 >> 1, coHalf = coG32 & 1;
    const int cis = zidx / KK, kd = zidx % KK;
    const int t = threadIdx.x;
    const int lane = t & 63, wv = t >> 6;
    const int ln15 = lane & 15, kg = lane >> 4;

    float* sout = slab + ((size_t)zidx*CO + coG32*32)*4096 + d0*256;
    const int z = d0 + kd - P;
    if ((unsigned)z >= 16u) {
        for (int m = t; m < 32*256; m += 256)
            sout[(size_t)(m >> 8)*4096 + (m & 255)] = 0.f;
        return;
    }

    __shared__ __align__(16) _Float16 sXh[8192];
    __shared__ __align__(16) _Float16 sXl[8192];
    __shared__ __align__(16) _Float16 zb[8];
    if (t < 8) zb[t] = (_Float16)0.f;

    int aoff[2];
    #pragma unroll
    for (int cf = 0; cf < 2; cf++) {
        const int s = (coHalf*32 + cf*16 + ln15)*4 + kg;
        aoff[cf] = (s ^ ((s >> 3) & 7)) * 8;
    }

    auto stage_X = [&](int ch) {
        const size_t b16 = ((size_t)ch*16 + z) * 8192;
        #pragma unroll
        for (int q = 0; q < 4; q++) {
            gld16(xh + b16 + (q*256 + t)*8, &sXh[(q*256 + t)*8]);
            gld16(xl + b16 + (q*256 + t)*8, &sXl[(q*256 + t)*8]);
        }
    };
    auto loadA = [&](int ch, int t2, half8* Ah, half8* Al) {
        const size_t b = ((size_t)((kd*K2 + t2)*NCOG64 + co64G)*NCH + ch) * 2048;
        #pragma unroll
        for (int cf = 0; cf < 2; cf++) {
            Ah[cf] = *(const half8*)&wh[b + aoff[cf]];
            Al[cf] = *(const half8*)&wl[b + aoff[cf]];
        }
    };

    f32x4 acc[2][4];
    #pragma unroll
    for (int a = 0; a < 2; a++)
        #pragma unroll
        for (int b = 0; b < 4; b++)
            #pragma unroll
            for (int r2 = 0; r2 < 4; r2++) acc[a][b][r2] = 0.f;

    const int ch0 = cis * NCHS;
    half8 nAh[2], nAl[2];
    stage_X(ch0);
    loadA(ch0, 0, nAh, nAl);
    asm volatile("s_waitcnt vmcnt(0)" ::: "memory");
    __syncthreads();

    for (int cc = 0; cc < NCHS; cc++) {
        const int ch = ch0 + cc;
        for (int t2 = 0; t2 < K2; t2++) {
            half8 cAh[2], cAl[2];
            #pragma unroll
            for (int cf = 0; cf < 2; cf++) { cAh[cf] = nAh[cf]; cAl[cf] = nAl[cf]; }
            if (t2 + 1 < K2)          loadA(ch, t2 + 1, nAh, nAl);
            else if (cc + 1 < NCHS)   loadA(ch + 1, 0, nAh, nAl);

            const int kh = t2 / KK, kw = t2 % KK;
            __builtin_amdgcn_s_setprio(1);
            #pragma unroll
            for (int f = 0; f < 4; f++) {
                const int h_in = wv*4 + f + kh - P;
                if ((unsigned)h_in < 16u) {
                    const int w_in = ln15 + kw - P;
                    const bool ok = (unsigned)w_in < 16u;
                    const int slot = ok ? (kg*256 + h_in*16 + (w_in ^ (kg << 1))) : 0;
                    const half8 Bh = ok ? *(const half8*)&sXh[slot*8] : *(const half8*)zb;
                    const half8 Bl = ok ? *(const half8*)&sXl[slot*8] : *(const half8*)zb;
                    #pragma unroll
                    for (int cf = 0; cf < 2; cf++) {
                        acc[cf][f] = __builtin_amdgcn_mfma_f32_16x16x32_f16(cAh[cf], Bh, acc[cf][f], 0, 0, 0);
                        acc[cf][f] = __builtin_amdgcn_mfma_f32_16x16x32_f16(cAh[cf], Bl, acc[cf][f], 0, 0, 0);
                        acc[cf][f] = __builtin_amdgcn_mfma_f32_16x16x32_f16(cAl[cf], Bh, acc[cf][f], 0, 0, 0);
                    }
                }
            }
            __builtin_amdgcn_s_setprio(0);
        }
        if (cc + 1 < NCHS) {
            __syncthreads();
            stage_X(ch + 1);
            asm volatile("s_waitcnt vmcnt(0)" ::: "memory");
            __syncthreads();
        }
    }

    #pragma unroll
    for (int cf = 0; cf < 2; cf++)
        #pragma unroll
        for (int f = 0; f < 4; f++)
            #pragma unroll
            for (int r2 = 0; r2 < 4; r2++)
                sout[(size_t)(cf*16 + kg*4 + r2)*4096 + wv*64 + f*16 + ln15] = acc[cf][f][r2];
}

// ---------------------------------------------------------------------------
// Reduce v2: 4 channels/thread -> 2x blocks (occupancy for the latency-bound
// reduces). Same output layouts as before (byte-identical).
// grid(16 z, CO/4).
// ---------------------------------------------------------------------------
template<int S, int RMODE, int OUT>
__global__ __launch_bounds__(256) void reduce_k(
    const float* __restrict__ pbuf, const float* __restrict__ addsrc,
    float* __restrict__ outf, _Float16* __restrict__ oh, _Float16* __restrict__ ol,
    int CO)
{
    const int z = blockIdx.x, c4 = blockIdx.y, v = threadIdx.x;
    float val[4];
    #pragma unroll
    for (int jj = 0; jj < 4; jj++) {
        const int c = c4*4 + jj;
        float a = 0.f;
        #pragma unroll
        for (int s = 0; s < S; s++)
            a += pbuf[((size_t)s*CO + c)*4096 + z*256 + v];
        a *= BN_S;
        if (RMODE == 3) a += addsrc[(size_t)c*4096 + z*256 + v];
        if (RMODE != 2) a = fmaxf(a, 0.f);
        val[jj] = a;
    }
    if (OUT == 0) {
        #pragma unroll
        for (int jj = 0; jj < 4; jj++)
            outf[(size_t)(c4*4 + jj)*4096 + z*256 + v] = val[jj];
    } else if (OUT == 1) {
        _Float16 hv[4], lv[4];
        #pragma unroll
        for (int jj = 0; jj < 4; jj++) {
            hv[jj] = (_Float16)val[jj];
            lv[jj] = (_Float16)(val[jj] - (float)hv[jj]);
        }
        const int oct = (c4 >> 1) & 3;
        const int vsw = v ^ (oct << 1);
        const size_t a16 = (((size_t)(c4 >> 3)*16 + z)*1024 + oct*256 + vsw)*8 + (c4 & 1)*4;
        *(uint2*)&oh[a16] = *(const uint2*)hv;
        *(uint2*)&ol[a16] = *(const uint2*)lv;
    } else {
        __shared__ float sm[4][4];
        #pragma unroll
        for (int jj = 0; jj < 4; jj++) {
            float m = val[jj];
            m = fmaxf(m, __shfl_xor(m, 1, 64));  m = fmaxf(m, __shfl_xor(m, 2, 64));
            m = fmaxf(m, __shfl_xor(m, 4, 64));  m = fmaxf(m, __shfl_xor(m, 8, 64));
            m = fmaxf(m, __shfl_xor(m, 16, 64)); m = fmaxf(m, __shfl_xor(m, 32, 64));
            if ((v & 63) == 0) sm[v >> 6][jj] = m;
        }
        __syncthreads();
        if (v < 4) {
            const float m = fmaxf(fmaxf(sm[0][v], sm[1][v]), fmaxf(sm[2][v], sm[3][v]));
            outf[z*CO + c4*4 + v] = m;
        }
    }
}

// ---------------------------------------------------------------------------
__global__ __launch_bounds__(256) void fc_k(
    const float* __restrict__ pp, const float* __restrict__ fcw,
    const float* __restrict__ fcb, float* __restrict__ out)
{
    __shared__ float sp[256];
    const int t = threadIdx.x;
    float m = pp[t];
    for (int zz = 1; zz < 16; zz++) m = fmaxf(m, pp[zz*256 + t]);
    sp[t] = m;
    __syncthreads();
    if (t < 20) {
        float s = fcb[t];
        for (int c = 0; c < 256; c++) s = fmaf(sp[c], fcw[c*20 + t], s);
        out[t] = s;
    }
}

// ---------------------------------------------------------------------------
extern "C" void kernel_launch(void* const* d_in, const int* in_sizes, int n_in,
                              void* d_out, int out_size, void* d_ws, size_t ws_size,
                              hipStream_t stream)
{
    const float* node_embedding = (const float*)d_in[0];
    const float* node_pos       = (const float*)d_in[1];
    const float* grid_pos       = (const float*)d_in[2];
    const int*   edge_index     = (const int*)d_in[3];
    const float* ew1 = (const float*)d_in[4];
    const float* eb1 = (const float*)d_in[5];
    const float* ew2 = (const float*)d_in[6];
    const float* eb2 = (const float*)d_in[7];
    const float* mw1 = (const float*)d_in[8];
    const float* mb1 = (const float*)d_in[9];
    const float* mw2 = (const float*)d_in[10];
    const float* mb2 = (const float*)d_in[11];
    const float* uw1 = (const float*)d_in[12];
    const float* ub1 = (const float*)d_in[13];
    const float* uw2 = (const float*)d_in[14];
    const float* ub2 = (const float*)d_in[15];
    const float* c1a = (const float*)d_in[16];
    const float* c1b = (const float*)d_in[17];
    const float* c1s = (const float*)d_in[18];
    const float* c2a = (const float*)d_in[19];
    const float* c2b = (const float*)d_in[20];
    const float* c2s = (const float*)d_in[21];
    const float* c3a = (const float*)d_in[22];
    const float* c3b = (const float*)d_in[23];
    const float* c3s = (const float*)d_in[24];
    const float* fcw = (const float*)d_in[25];
    const float* fcb = (const float*)d_in[26];
    float* out = (float*)d_out;
    const int* edge_i = edge_index;   // row 0

    float* ws = (float*)d_ws;
    float* a_node = ws;                ws += 262144;
    float* g_vox  = ws;                ws += 262144;
    float* n_node = ws;                ws += 262144;
    float* W_mu   = ws;                ws += 4096;
    float* b_mu   = ws;                ws += 64;
    _Float16* wemt_h = (_Float16*)ws;  ws += 2048;
    _Float16* wemt_l = (_Float16*)ws;  ws += 2048;
    _Float16* x0h = (_Float16*)ws;     ws += 131072;
    _Float16* x0l = (_Float16*)ws;     ws += 131072;
    _Float16* t2h = (_Float16*)ws;     ws += 262144;
    _Float16* t2l = (_Float16*)ws;     ws += 262144;
    _Float16* x2h = (_Float16*)ws;     ws += 262144;
    _Float16* x2l = (_Float16*)ws;     ws += 262144;
    _Float16* t3h = (_Float16*)ws;     ws += 524288;
    _Float16* t3l = (_Float16*)ws;     ws += 524288;
    float* u2 = ws;                    ws += 524288;
    float* u3 = ws;                    ws += 1048576;
    float* slab = ws;                  ws += 5242880;
    float* poolPart = ws;              ws += 4096;
    _Float16* wh = (_Float16*)ws;      ws += 4585472;   // 9170944 f16
    _Float16* wl = (_Float16*)ws;      ws += 4585472;
    // aliases valid after edge_kernel (node tables dead):
    _Float16* t1h = (_Float16*)a_node;
    _Float16* t1l = (_Float16*)(a_node + 131072);
    float* u1 = g_vox;
    _Float16* x1h = (_Float16*)n_node;
    _Float16* x1l = (_Float16*)(n_node + 131072);

    _Float16* w1a_h = wh + 0;       _Float16* w1a_l = wl + 0;
    _Float16* w1b_h = wh + 110592;  _Float16* w1b_l = wl + 110592;
    _Float16* w1s_h = wh + 221184;  _Float16* w1s_l = wl + 221184;
    _Float16* w2a_h = wh + 733184;  _Float16* w2a_l = wl + 733184;
    _Float16* w2b_h = wh + 954368;  _Float16* w2b_l = wl + 954368;
    _Float16* w2s_h = wh + 1396736; _Float16* w2s_l = wl + 1396736;
    _Float16* w3a_h = wh + 2420736; _Float16* w3a_l = wl + 2420736;
    _Float16* w3b_h = wh + 3305472; _Float16* w3b_l = wl + 3305472;
    _Float16* w3s_h = wh + 5074944; _Float16* w3s_l = wl + 5074944;

    // ---- merged weight transpose + split: 2 dispatches ----
    {
        WSArgs a27;
        a27.n = 6;
        a27.src[0] = c1a; a27.dh[0] = w1a_h; a27.dl[0] = w1a_l; a27.CI[0] = 64;  a27.NCOG[0] = 1; a27.NCH[0] = 2;
        a27.src[1] = c1b; a27.dh[1] = w1b_h; a27.dl[1] = w1b_l; a27.CI[1] = 64;  a27.NCOG[1] = 1; a27.NCH[1] = 2;
        a27.src[2] = c2a; a27.dh[2] = w2a_h; a27.dl[2] = w2a_l; a27.CI[2] = 64;  a27.NCOG[2] = 2; a27.NCH[2] = 2;
        a27.src[3] = c2b; a27.dh[3] = w2b_h; a27.dl[3] = w2b_l; a27.CI[3] = 128; a27.NCOG[3] = 2; a27.NCH[3] = 4;
        a27.src[4] = c3a; a27.dh[4] = w3a_h; a27.dl[4] = w3a_l; a27.CI[4] = 128; a27.NCOG[4] = 4; a27.NCH[4] = 4;
        a27.src[5] = c3b; a27.dh[5] = w3b_h; a27.dl[5] = w3b_l; a27.CI[5] = 256; a27.NCOG[5] = 4; a27.NCH[5] = 8;
        a27.ofs[0] = 0;    a27.ofs[1] = 128;  a27.ofs[2] = 256;  a27.ofs[3] = 512;
        a27.ofs[4] = 1024; a27.ofs[5] = 2048; a27.ofs[6] = 4096;
        hipLaunchKernelGGL((wsplit_k<27>), dim3(4096), dim3(256), 0, stream, a27);

        WSArgs a125;
        a125.n = 3;
        a125.src[0] = c1s; a125.dh[0] = w1s_h; a125.dl[0] = w1s_l; a125.CI[0] = 64;  a125.NCOG[0] = 1; a125.NCH[0] = 2;
        a125.src[1] = c2s; a125.dh[1] = w2s_h; a125.dl[1] = w2s_l; a125.CI[1] = 64;  a125.NCOG[1] = 2; a125.NCH[1] = 2;
        a125.src[2] = c3s; a125.dh[2] = w3s_h; a125.dl[2] = w3s_l; a125.CI[2] = 128; a125.NCOG[2] = 4; a125.NCH[2] = 4;
        a125.ofs[0] = 0; a125.ofs[1] = 128; a125.ofs[2] = 384; a125.ofs[3] = 1408;
        a125.ofs[4] = 0; a125.ofs[5] = 0; a125.ofs[6] = 0;
        hipLaunchKernelGGL((wsplit_k<125>), dim3(1408), dim3(256), 0, stream, a125);
    }

    // ---- merged MPNN prep (1 dispatch) ----
    hipLaunchKernelGGL(prep_all_k, dim3(4096), dim3(64), 0, stream,
                       node_embedding, node_pos, grid_pos, ew1, eb1, mw1, mb1, eb2,
                       ew2, mw2, uw1, mb2, ub1,
                       a_node, g_vox, n_node, W_mu, b_mu, wemt_h, wemt_l);
    hipLaunchKernelGGL(edge_kernel, dim3(4096), dim3(256), 0, stream,
                       edge_i, a_node, g_vox, n_node, wemt_h, wemt_l,
                       W_mu, b_mu, uw2, ub2, x0h, x0l);

    // ---- ResNet3D ----
    // Block 1: 64 -> 64
    hipLaunchKernelGGL((conv_mfma_k<3,64,2,2,false>), dim3(16,2,6), dim3(256), 0, stream, x0h, x0l, w1a_h, w1a_l, slab);
    hipLaunchKernelGGL((reduce_k<6,1,1>), dim3(16,16), dim3(256), 0, stream, slab, (const float*)nullptr, (float*)nullptr, t1h, t1l, 64);
    hipLaunchKernelGGL((conv_mfma_k<3,64,2,2,false>), dim3(16,2,6), dim3(256), 0, stream, t1h, t1l, w1b_h, w1b_l, slab);
    hipLaunchKernelGGL((reduce_k<6,2,0>), dim3(16,16), dim3(256), 0, stream, slab, (const float*)nullptr, u1, (_Float16*)nullptr, (_Float16*)nullptr, 64);
    hipLaunchKernelGGL((conv_mfma_k<5,64,2,2,false>), dim3(16,2,10), dim3(256), 0, stream, x0h, x0l, w1s_h, w1s_l, slab);
    hipLaunchKernelGGL((reduce_k<10,3,1>), dim3(16,16), dim3(256), 0, stream, slab, u1, (float*)nullptr, x1h, x1l, 64);
    // Block 2: 64 -> 128
    hipLaunchKernelGGL((conv_mfma_k<3,64,4,2,true>), dim3(16,4,6), dim3(256), 0, stream, x1h, x1l, w2a_h, w2a_l, slab);
    hipLaunchKernelGGL((reduce_k<6,1,1>), dim3(16,32), dim3(256), 0, stream, slab, (const float*)nullptr, (float*)nullptr, t2h, t2l, 128);
    hipLaunchKernelGGL((conv_mfma_k<3,128,4,2,true>), dim3(16,4,6), dim3(256), 0, stream, t2h, t2l, w2b_h, w2b_l, slab);
    hipLaunchKernelGGL((reduce_k<6,2,0>), dim3(16,32), dim3(256), 0, stream, slab, (const float*)nullptr, u2, (_Float16*)nullptr, (_Float16*)nullptr, 128);
    hipLaunchKernelGGL((conv_mfma_k<5,64,4,2,true>), dim3(16,4,10), dim3(256), 0, stream, x1h, x1l, w2s_h, w2s_l, slab);
    hipLaunchKernelGGL((reduce_k<10,3,1>), dim3(16,32), dim3(256), 0, stream, slab, u2, (float*)nullptr, x2h, x2l, 128);
    // Block 3: 128 -> 256
    hipLaunchKernelGGL((conv_mfma_k<3,128,8,1,true>), dim3(16,8,3), dim3(256), 0, stream, x2h, x2l, w3a_h, w3a_l, slab);
    hipLaunchKernelGGL((reduce_k<3,1,1>), dim3(16,64), dim3(256), 0, stream, slab, (const float*)nullptr, (float*)nullptr, t3h, t3l, 256);
    hipLaunchKernelGGL((conv_mfma_k<3,256,8,1,true>), dim3(16,8,3), dim3(256), 0, stream, t3h, t3l, w3b_h, w3b_l, slab);
    hipLaunchKernelGGL((reduce_k<3,2,0>), dim3(16,64), dim3(256), 0, stream, slab, (const float*)nullptr, u3, (_Float16*)nullptr, (_Float16*)nullptr, 256);
    hipLaunchKernelGGL((conv_mfma_k<5,128,8,1,true>), dim3(16,8,5), dim3(256), 0, stream, x2h, x2l, w3s_h, w3s_l, slab);
    hipLaunchKernelGGL((reduce_k<5,3,2>), dim3(16,64), dim3(256), 0, stream, slab, u3, poolPart, (_Float16*)nullptr, (_Float16*)nullptr, 256);

    hipLaunchKernelGGL(fc_k, dim3(1), dim3(256), 0, stream, poolPart, fcw, fcb, out);

    (void)in_sizes; (void)n_in; (void)out_size; (void)ws_size;
}